// Round 1
// baseline (862.529 us; speedup 1.0000x reference)
//
#include <hip/hip_runtime.h>
#include <cstdint>

// ---------------- graph preprocessing ----------------

__global__ __launch_bounds__(256) void k_count(const int* __restrict__ dst, int* __restrict__ cnt, int E) {
    int e = blockIdx.x * 256 + threadIdx.x;
    if (e < E) atomicAdd(&cnt[dst[e]], 1);
}

__global__ __launch_bounds__(256) void k_dinv(const int* __restrict__ cnt, float* __restrict__ dinv, int N) {
    int i = blockIdx.x * 256 + threadIdx.x;
    if (i < N) dinv[i] = rsqrtf((float)(cnt[i] + 1));   // +1 self-loop
}

// single-block exclusive scan of cnt[N] -> rowstart[N+1]
__global__ __launch_bounds__(1024) void k_scan(const int* __restrict__ cnt, int* __restrict__ rowstart, int N) {
    __shared__ int ls[1024];
    int t = threadIdx.x;
    int chunk = (N + 1023) >> 10;
    int begin = t * chunk; if (begin > N) begin = N;
    int end = begin + chunk; if (end > N) end = N;
    int s = 0;
    for (int i = begin; i < end; i++) s += cnt[i];
    ls[t] = s;
    __syncthreads();
    for (int off = 1; off < 1024; off <<= 1) {
        int o = (t >= off) ? ls[t - off] : 0;
        __syncthreads();
        ls[t] += o;
        __syncthreads();
    }
    int run = ls[t] - s;   // exclusive prefix of this thread's chunk
    for (int i = begin; i < end; i++) { rowstart[i] = run; run += cnt[i]; }
    if (t == 1023) rowstart[N] = ls[1023];
}

__global__ __launch_bounds__(256) void k_scatter(const int* __restrict__ src, const int* __restrict__ dst,
                                                 const int* __restrict__ rowstart, int* __restrict__ cursor,
                                                 int* __restrict__ csr, int E) {
    int e = blockIdx.x * 256 + threadIdx.x;
    if (e >= E) return;
    int d = dst[e];
    int pos = rowstart[d] + atomicAdd(&cursor[d], 1);
    csr[pos] = src[e];
}

// ---------------- GEMM: C[M x NC] = A[M x 128] @ B[128 x NC] ----------------
// 64x64 tile, 4x4 microtile, K staged in two 64-chunks through LDS.

__global__ __launch_bounds__(256) void k_gemm(const float* __restrict__ A, const float* __restrict__ B,
                                              float* __restrict__ C, int M, int NC) {
    __shared__ float As[64][68];   // 68: row stride 272B (16B-aligned, conflict-light)
    __shared__ float Bs[64][64];
    int t = threadIdx.x;
    int row0 = blockIdx.x * 64;
    int col0 = blockIdx.y * 64;
    int tc = (t & 15) << 2;        // col offset 0..60
    int tr = (t >> 4) << 2;        // row offset 0..60
    float acc[4][4] = {};

    for (int kt = 0; kt < 128; kt += 64) {
        // stage A: 64 rows x 64 k  (1024 float4, 4 per thread)
        for (int f = t; f < 1024; f += 256) {
            int r = f >> 4, k4 = (f & 15) << 2;
            float4 v = make_float4(0.f, 0.f, 0.f, 0.f);
            int row = row0 + r;
            if (row < M) v = *(const float4*)(A + (size_t)row * 128 + kt + k4);
            *(float4*)(&As[r][k4]) = v;
        }
        // stage B: 64 k x 64 cols
        for (int f = t; f < 1024; f += 256) {
            int k = f >> 4, c4 = (f & 15) << 2;
            int c = col0 + c4;
            float4 v = make_float4(0.f, 0.f, 0.f, 0.f);
            if (c + 3 < NC) {
                v = *(const float4*)(B + (size_t)(kt + k) * NC + c);
            } else {
                float tmp[4] = {0.f, 0.f, 0.f, 0.f};
                for (int j = 0; j < 4; j++) if (c + j < NC) tmp[j] = B[(size_t)(kt + k) * NC + c + j];
                v = make_float4(tmp[0], tmp[1], tmp[2], tmp[3]);
            }
            *(float4*)(&Bs[k][c4]) = v;
        }
        __syncthreads();
        for (int k = 0; k < 64; k += 4) {
            float4 b0 = *(const float4*)(&Bs[k + 0][tc]);
            float4 b1 = *(const float4*)(&Bs[k + 1][tc]);
            float4 b2 = *(const float4*)(&Bs[k + 2][tc]);
            float4 b3 = *(const float4*)(&Bs[k + 3][tc]);
#pragma unroll
            for (int i = 0; i < 4; i++) {
                float4 a = *(const float4*)(&As[tr + i][k]);
                acc[i][0] += a.x * b0.x + a.y * b1.x + a.z * b2.x + a.w * b3.x;
                acc[i][1] += a.x * b0.y + a.y * b1.y + a.z * b2.y + a.w * b3.y;
                acc[i][2] += a.x * b0.z + a.y * b1.z + a.z * b2.z + a.w * b3.z;
                acc[i][3] += a.x * b0.w + a.y * b1.w + a.z * b2.w + a.w * b3.w;
            }
        }
        __syncthreads();
    }

#pragma unroll
    for (int i = 0; i < 4; i++) {
        int row = row0 + tr + i;
        if (row >= M) continue;
#pragma unroll
        for (int j = 0; j < 4; j++) {
            int col = col0 + tc + j;
            if (col < NC) C[(size_t)row * NC + col] = acc[i][j];
        }
    }
}

// ---------------- aggregation: out[n] = (sum_{s in in(n)} H[s]*dinv[s] + H[n]*dinv[n]) * dinv[n] + b ----------------
// 128 threads per node (one feature channel each), 2 nodes per block.

__global__ __launch_bounds__(256) void k_aggregate(const float* __restrict__ H, const int* __restrict__ csr,
                                                   const int* __restrict__ rowstart, const float* __restrict__ dinv,
                                                   const float* __restrict__ bias, float* __restrict__ out,
                                                   int N, int D) {
    int node = blockIdx.x * 2 + (threadIdx.x >> 7);
    int c = threadIdx.x & 127;
    if (node >= N || c >= D) return;
    float dn = dinv[node];
    int s0 = rowstart[node], s1 = rowstart[node + 1];
    float acc = 0.f;
    for (int j = s0; j < s1; j++) {
        int s = csr[j];
        acc += H[(size_t)s * D + c] * dinv[s];
    }
    acc += H[(size_t)node * D + c] * dn;
    out[(size_t)node * D + c] = acc * dn + bias[c];
}

// ---------------- BatchNorm (training-mode) ----------------

__global__ __launch_bounds__(256) void k_bn_stats(const float* __restrict__ H, float* __restrict__ sums, int N) {
    __shared__ float ls[256], ls2[256];
    int c = threadIdx.x & 127;
    int half = threadIdx.x >> 7;
    float s = 0.f, s2 = 0.f;
    for (int r = blockIdx.x * 2 + half; r < N; r += gridDim.x * 2) {
        float v = H[(size_t)r * 128 + c];
        s += v; s2 += v * v;
    }
    ls[threadIdx.x] = s; ls2[threadIdx.x] = s2;
    __syncthreads();
    if (threadIdx.x < 128) {
        atomicAdd(&sums[c], ls[threadIdx.x] + ls[threadIdx.x + 128]);
        atomicAdd(&sums[128 + c], ls2[threadIdx.x] + ls2[threadIdx.x + 128]);
    }
}

__global__ __launch_bounds__(256) void k_bn_relu(float* __restrict__ H, const float* __restrict__ sums,
                                                 const float* __restrict__ g, const float* __restrict__ bt, int N) {
    float invN = 1.0f / (float)N;
    size_t total = (size_t)N * 128;
    for (size_t i = (size_t)blockIdx.x * 256 + threadIdx.x; i < total; i += (size_t)gridDim.x * 256) {
        int c = (int)(i & 127);
        float mu = sums[c] * invN;
        float var = sums[128 + c] * invN - mu * mu;
        float w = rsqrtf(var + 1e-5f) * g[c];
        float v = (H[i] - mu) * w + bt[c];
        H[i] = fmaxf(v, 0.f);
    }
}

// ---------------- log_softmax over rows of D (<=64) ----------------

__global__ __launch_bounds__(256) void k_logsoftmax(float* __restrict__ out, int N, int D) {
    int wid = threadIdx.x >> 6;
    int lane = threadIdx.x & 63;
    int row = blockIdx.x * 4 + wid;
    if (row >= N) return;
    float v = (lane < D) ? out[(size_t)row * D + lane] : -1e30f;
    float m = v;
#pragma unroll
    for (int off = 32; off; off >>= 1) m = fmaxf(m, __shfl_xor(m, off, 64));
    float e = (lane < D) ? expf(v - m) : 0.f;
    float s = e;
#pragma unroll
    for (int off = 32; off; off >>= 1) s += __shfl_xor(s, off, 64);
    if (lane < D) out[(size_t)row * D + lane] = (v - m) - logf(s);
}

// ---------------- launch ----------------

extern "C" void kernel_launch(void* const* d_in, const int* in_sizes, int n_in,
                              void* d_out, int out_size, void* d_ws, size_t ws_size,
                              hipStream_t stream) {
    const float* x   = (const float*)d_in[0];
    const int*   ei  = (const int*)d_in[1];
    const float* W0  = (const float*)d_in[2];
    const float* b0  = (const float*)d_in[3];
    const float* W1  = (const float*)d_in[4];
    const float* b1  = (const float*)d_in[5];
    const float* W2  = (const float*)d_in[6];
    const float* b2  = (const float*)d_in[7];
    const float* g0  = (const float*)d_in[8];
    const float* bt0 = (const float*)d_in[9];
    const float* g1  = (const float*)d_in[10];
    const float* bt1 = (const float*)d_in[11];
    float* out = (float*)d_out;

    int N    = in_sizes[0] / 128;
    int E    = in_sizes[1] / 2;
    int DOUT = in_sizes[7];          // b2 length

    const int* srcp = ei;
    const int* dstp = ei + E;

    char* wsp = (char*)d_ws;
    int*   cnt      = (int*)wsp;   wsp += (size_t)N * 4;
    int*   rowstart = (int*)wsp;   wsp += (size_t)(N + 1) * 4;
    int*   cursor   = (int*)wsp;   wsp += (size_t)N * 4;
    int*   csr      = (int*)wsp;   wsp += (size_t)E * 4;
    float* dinv     = (float*)wsp; wsp += (size_t)N * 4;
    float* stats    = (float*)wsp; wsp += 256 * 4;
    float* Hg       = (float*)wsp; wsp += (size_t)N * 128 * 4;
    float* Ha       = (float*)wsp; wsp += (size_t)N * 128 * 4;

    hipMemsetAsync(cnt, 0, (size_t)N * 4, stream);
    hipMemsetAsync(cursor, 0, (size_t)N * 4, stream);

    k_count<<<(E + 255) / 256, 256, 0, stream>>>(dstp, cnt, E);
    k_dinv<<<(N + 255) / 256, 256, 0, stream>>>(cnt, dinv, N);
    k_scan<<<1, 1024, 0, stream>>>(cnt, rowstart, N);
    k_scatter<<<(E + 255) / 256, 256, 0, stream>>>(srcp, dstp, rowstart, cursor, csr, E);

    int agg_blocks = (N + 1) / 2;

    // layer 1
    k_gemm<<<dim3((N + 63) / 64, 2), 256, 0, stream>>>(x, W0, Hg, N, 128);
    k_aggregate<<<agg_blocks, 256, 0, stream>>>(Hg, csr, rowstart, dinv, b0, Ha, N, 128);
    hipMemsetAsync(stats, 0, 256 * 4, stream);
    k_bn_stats<<<512, 256, 0, stream>>>(Ha, stats, N);
    k_bn_relu<<<2048, 256, 0, stream>>>(Ha, stats, g0, bt0, N);

    // layer 2
    k_gemm<<<dim3((N + 63) / 64, 2), 256, 0, stream>>>(Ha, W1, Hg, N, 128);
    k_aggregate<<<agg_blocks, 256, 0, stream>>>(Hg, csr, rowstart, dinv, b1, Ha, N, 128);
    hipMemsetAsync(stats, 0, 256 * 4, stream);
    k_bn_stats<<<512, 256, 0, stream>>>(Ha, stats, N);
    k_bn_relu<<<2048, 256, 0, stream>>>(Ha, stats, g1, bt1, N);

    // layer 3 (no BN, no relu)
    k_gemm<<<dim3((N + 63) / 64, (DOUT + 63) / 64), 256, 0, stream>>>(Ha, W2, Hg, N, DOUT);
    k_aggregate<<<agg_blocks, 256, 0, stream>>>(Hg, csr, rowstart, dinv, b2, out, N, DOUT);
    k_logsoftmax<<<(N + 3) / 4, 256, 0, stream>>>(out, N, DOUT);
}

// Round 2
// 613.742 us; speedup vs baseline: 1.4054x; 1.4054x over previous
//
#include <hip/hip_runtime.h>
#include <cstdint>

// ---------------- graph preprocessing ----------------

__global__ __launch_bounds__(256) void k_count(const int* __restrict__ dst, int* __restrict__ cnt, int E) {
    int e = blockIdx.x * 256 + threadIdx.x;
    if (e < E) atomicAdd(&cnt[dst[e]], 1);
}

__global__ __launch_bounds__(256) void k_dinv(const int* __restrict__ cnt, float* __restrict__ dinv, int N) {
    int i = blockIdx.x * 256 + threadIdx.x;
    if (i < N) dinv[i] = rsqrtf((float)(cnt[i] + 1));   // +1 self-loop
}

// single-block exclusive scan of cnt[N] -> rowstart[N+1]
__global__ __launch_bounds__(1024) void k_scan(const int* __restrict__ cnt, int* __restrict__ rowstart, int N) {
    __shared__ int ls[1024];
    int t = threadIdx.x;
    int chunk = (N + 1023) >> 10;
    int begin = t * chunk; if (begin > N) begin = N;
    int end = begin + chunk; if (end > N) end = N;
    int s = 0;
    for (int i = begin; i < end; i++) s += cnt[i];
    ls[t] = s;
    __syncthreads();
    for (int off = 1; off < 1024; off <<= 1) {
        int o = (t >= off) ? ls[t - off] : 0;
        __syncthreads();
        ls[t] += o;
        __syncthreads();
    }
    int run = ls[t] - s;   // exclusive prefix of this thread's chunk
    for (int i = begin; i < end; i++) { rowstart[i] = run; run += cnt[i]; }
    if (t == 1023) rowstart[N] = ls[1023];
}

__global__ __launch_bounds__(256) void k_scatter(const int* __restrict__ src, const int* __restrict__ dst,
                                                 const int* __restrict__ rowstart, int* __restrict__ cursor,
                                                 int* __restrict__ csr, int E) {
    int e = blockIdx.x * 256 + threadIdx.x;
    if (e >= E) return;
    int d = dst[e];
    int pos = rowstart[d] + atomicAdd(&cursor[d], 1);
    csr[pos] = src[e];
}

// ---------------- GEMM: C[M x NC] = (A[M x 128] @ B[128 x NC]) * dscale[row] ----------------
// 64x64 tile, 4x4 microtile, K staged in two 64-chunks through LDS.
// dscale folds the source-side dinv[s] into the matrix so the aggregate
// gather has no dependent dinv load.

__global__ __launch_bounds__(256) void k_gemm(const float* __restrict__ A, const float* __restrict__ B,
                                              const float* __restrict__ dscale,
                                              float* __restrict__ C, int M, int NC) {
    __shared__ float As[64][68];
    __shared__ float Bs[64][64];
    int t = threadIdx.x;
    int row0 = blockIdx.x * 64;
    int col0 = blockIdx.y * 64;
    int tc = (t & 15) << 2;        // col offset 0..60
    int tr = (t >> 4) << 2;        // row offset 0..60
    float acc[4][4] = {};

    for (int kt = 0; kt < 128; kt += 64) {
        for (int f = t; f < 1024; f += 256) {
            int r = f >> 4, k4 = (f & 15) << 2;
            float4 v = make_float4(0.f, 0.f, 0.f, 0.f);
            int row = row0 + r;
            if (row < M) v = *(const float4*)(A + (size_t)row * 128 + kt + k4);
            *(float4*)(&As[r][k4]) = v;
        }
        for (int f = t; f < 1024; f += 256) {
            int k = f >> 4, c4 = (f & 15) << 2;
            int c = col0 + c4;
            float4 v = make_float4(0.f, 0.f, 0.f, 0.f);
            if (c + 3 < NC) {
                v = *(const float4*)(B + (size_t)(kt + k) * NC + c);
            } else {
                float tmp[4] = {0.f, 0.f, 0.f, 0.f};
                for (int j = 0; j < 4; j++) if (c + j < NC) tmp[j] = B[(size_t)(kt + k) * NC + c + j];
                v = make_float4(tmp[0], tmp[1], tmp[2], tmp[3]);
            }
            *(float4*)(&Bs[k][c4]) = v;
        }
        __syncthreads();
        for (int k = 0; k < 64; k += 4) {
            float4 b0 = *(const float4*)(&Bs[k + 0][tc]);
            float4 b1 = *(const float4*)(&Bs[k + 1][tc]);
            float4 b2 = *(const float4*)(&Bs[k + 2][tc]);
            float4 b3 = *(const float4*)(&Bs[k + 3][tc]);
#pragma unroll
            for (int i = 0; i < 4; i++) {
                float4 a = *(const float4*)(&As[tr + i][k]);
                acc[i][0] += a.x * b0.x + a.y * b1.x + a.z * b2.x + a.w * b3.x;
                acc[i][1] += a.x * b0.y + a.y * b1.y + a.z * b2.y + a.w * b3.y;
                acc[i][2] += a.x * b0.z + a.y * b1.z + a.z * b2.z + a.w * b3.z;
                acc[i][3] += a.x * b0.w + a.y * b1.w + a.z * b2.w + a.w * b3.w;
            }
        }
        __syncthreads();
    }

#pragma unroll
    for (int i = 0; i < 4; i++) {
        int row = row0 + tr + i;
        if (row >= M) continue;
        float dn = dscale[row];
#pragma unroll
        for (int j = 0; j < 4; j++) {
            int col = col0 + tc + j;
            if (col < NC) C[(size_t)row * NC + col] = acc[i][j] * dn;
        }
    }
}

// ---------------- aggregation ----------------
// Hs rows are pre-scaled by dinv[src]. out[n] = (sum_in Hs[s] + Hs[n]) * dinv[n] + b
// TPN threads per node, float4 per thread, edge loop unrolled 8x for MLP.

template<int TPN>
__global__ __launch_bounds__(256) void k_aggregate(const float* __restrict__ Hs, const int* __restrict__ csr,
                                                   const int* __restrict__ rowstart, const float* __restrict__ dinv,
                                                   const float* __restrict__ bias, float* __restrict__ out,
                                                   int N, int D) {
    constexpr int NPB = 256 / TPN;
    int node = blockIdx.x * NPB + threadIdx.x / TPN;
    int lane = threadIdx.x % TPN;
    int c = lane << 2;
    if (node >= N) return;
    bool act = c < D;

    int s0 = rowstart[node], s1 = rowstart[node + 1];
    float ax = 0.f, ay = 0.f, az = 0.f, aw = 0.f;

    int j = s0;
    for (; j + 8 <= s1; j += 8) {
        int i0 = csr[j + 0], i1 = csr[j + 1], i2 = csr[j + 2], i3 = csr[j + 3];
        int i4 = csr[j + 4], i5 = csr[j + 5], i6 = csr[j + 6], i7 = csr[j + 7];
        if (act) {
            float4 v0 = *(const float4*)(Hs + (size_t)i0 * D + c);
            float4 v1 = *(const float4*)(Hs + (size_t)i1 * D + c);
            float4 v2 = *(const float4*)(Hs + (size_t)i2 * D + c);
            float4 v3 = *(const float4*)(Hs + (size_t)i3 * D + c);
            float4 v4 = *(const float4*)(Hs + (size_t)i4 * D + c);
            float4 v5 = *(const float4*)(Hs + (size_t)i5 * D + c);
            float4 v6 = *(const float4*)(Hs + (size_t)i6 * D + c);
            float4 v7 = *(const float4*)(Hs + (size_t)i7 * D + c);
            ax += v0.x; ay += v0.y; az += v0.z; aw += v0.w;
            ax += v1.x; ay += v1.y; az += v1.z; aw += v1.w;
            ax += v2.x; ay += v2.y; az += v2.z; aw += v2.w;
            ax += v3.x; ay += v3.y; az += v3.z; aw += v3.w;
            ax += v4.x; ay += v4.y; az += v4.z; aw += v4.w;
            ax += v5.x; ay += v5.y; az += v5.z; aw += v5.w;
            ax += v6.x; ay += v6.y; az += v6.z; aw += v6.w;
            ax += v7.x; ay += v7.y; az += v7.z; aw += v7.w;
        }
    }
    for (; j < s1; j++) {
        int s = csr[j];
        if (act) {
            float4 v = *(const float4*)(Hs + (size_t)s * D + c);
            ax += v.x; ay += v.y; az += v.z; aw += v.w;
        }
    }

    if (act) {
        float4 self = *(const float4*)(Hs + (size_t)node * D + c);
        float dn = dinv[node];
        float4 b4 = *(const float4*)(bias + c);
        float4 r;
        r.x = (ax + self.x) * dn + b4.x;
        r.y = (ay + self.y) * dn + b4.y;
        r.z = (az + self.z) * dn + b4.z;
        r.w = (aw + self.w) * dn + b4.w;
        *(float4*)(out + (size_t)node * D + c) = r;
    }
}

// ---------------- BatchNorm (training-mode) ----------------

__global__ __launch_bounds__(256) void k_bn_stats(const float* __restrict__ H, float* __restrict__ sums, int N) {
    __shared__ float ls[256], ls2[256];
    int c = threadIdx.x & 127;
    int half = threadIdx.x >> 7;
    float s = 0.f, s2 = 0.f;
    for (int r = blockIdx.x * 2 + half; r < N; r += gridDim.x * 2) {
        float v = H[(size_t)r * 128 + c];
        s += v; s2 += v * v;
    }
    ls[threadIdx.x] = s; ls2[threadIdx.x] = s2;
    __syncthreads();
    if (threadIdx.x < 128) {
        atomicAdd(&sums[c], ls[threadIdx.x] + ls[threadIdx.x + 128]);
        atomicAdd(&sums[128 + c], ls2[threadIdx.x] + ls2[threadIdx.x + 128]);
    }
}

__global__ __launch_bounds__(256) void k_bn_relu(float* __restrict__ H, const float* __restrict__ sums,
                                                 const float* __restrict__ g, const float* __restrict__ bt, int N) {
    float invN = 1.0f / (float)N;
    size_t total = (size_t)N * 128;
    for (size_t i = (size_t)blockIdx.x * 256 + threadIdx.x; i < total; i += (size_t)gridDim.x * 256) {
        int c = (int)(i & 127);
        float mu = sums[c] * invN;
        float var = sums[128 + c] * invN - mu * mu;
        float w = rsqrtf(var + 1e-5f) * g[c];
        float v = (H[i] - mu) * w + bt[c];
        H[i] = fmaxf(v, 0.f);
    }
}

// ---------------- log_softmax over rows of D (<=64) ----------------

__global__ __launch_bounds__(256) void k_logsoftmax(float* __restrict__ out, int N, int D) {
    int wid = threadIdx.x >> 6;
    int lane = threadIdx.x & 63;
    int row = blockIdx.x * 4 + wid;
    if (row >= N) return;
    float v = (lane < D) ? out[(size_t)row * D + lane] : -1e30f;
    float m = v;
#pragma unroll
    for (int off = 32; off; off >>= 1) m = fmaxf(m, __shfl_xor(m, off, 64));
    float e = (lane < D) ? expf(v - m) : 0.f;
    float s = e;
#pragma unroll
    for (int off = 32; off; off >>= 1) s += __shfl_xor(s, off, 64);
    if (lane < D) out[(size_t)row * D + lane] = (v - m) - logf(s);
}

// ---------------- launch ----------------

extern "C" void kernel_launch(void* const* d_in, const int* in_sizes, int n_in,
                              void* d_out, int out_size, void* d_ws, size_t ws_size,
                              hipStream_t stream) {
    const float* x   = (const float*)d_in[0];
    const int*   ei  = (const int*)d_in[1];
    const float* W0  = (const float*)d_in[2];
    const float* b0  = (const float*)d_in[3];
    const float* W1  = (const float*)d_in[4];
    const float* b1  = (const float*)d_in[5];
    const float* W2  = (const float*)d_in[6];
    const float* b2  = (const float*)d_in[7];
    const float* g0  = (const float*)d_in[8];
    const float* bt0 = (const float*)d_in[9];
    const float* g1  = (const float*)d_in[10];
    const float* bt1 = (const float*)d_in[11];
    float* out = (float*)d_out;

    int N    = in_sizes[0] / 128;
    int E    = in_sizes[1] / 2;
    int DOUT = in_sizes[7];          // b2 length

    const int* srcp = ei;
    const int* dstp = ei + E;

    // 256B-aligned workspace carve-up (float4 loads need 16B alignment)
    size_t off = 0;
    auto carve = [&](size_t bytes) { size_t o = off; off += (bytes + 255) & ~(size_t)255; return (char*)d_ws + o; };
    int*   cnt      = (int*)carve((size_t)N * 4);
    int*   rowstart = (int*)carve((size_t)(N + 1) * 4);
    int*   cursor   = (int*)carve((size_t)N * 4);
    int*   csr      = (int*)carve((size_t)E * 4);
    float* dinv     = (float*)carve((size_t)N * 4);
    float* stats    = (float*)carve(256 * 4);
    float* Hg       = (float*)carve((size_t)N * 128 * 4);
    float* Ha       = (float*)carve((size_t)N * 128 * 4);

    hipMemsetAsync(cnt, 0, (size_t)N * 4, stream);
    hipMemsetAsync(cursor, 0, (size_t)N * 4, stream);

    k_count<<<(E + 255) / 256, 256, 0, stream>>>(dstp, cnt, E);
    k_dinv<<<(N + 255) / 256, 256, 0, stream>>>(cnt, dinv, N);
    k_scan<<<1, 1024, 0, stream>>>(cnt, rowstart, N);
    k_scatter<<<(E + 255) / 256, 256, 0, stream>>>(srcp, dstp, rowstart, cursor, csr, E);

    int aggN_blocks  = (N + 7) / 8;    // TPN=32, 8 nodes/block
    int aggO_blocks  = (N + 15) / 16;  // TPN=16, 16 nodes/block

    // layer 1
    k_gemm<<<dim3((N + 63) / 64, 2), 256, 0, stream>>>(x, W0, dinv, Hg, N, 128);
    k_aggregate<32><<<aggN_blocks, 256, 0, stream>>>(Hg, csr, rowstart, dinv, b0, Ha, N, 128);
    hipMemsetAsync(stats, 0, 256 * 4, stream);
    k_bn_stats<<<512, 256, 0, stream>>>(Ha, stats, N);
    k_bn_relu<<<2048, 256, 0, stream>>>(Ha, stats, g0, bt0, N);

    // layer 2
    k_gemm<<<dim3((N + 63) / 64, 2), 256, 0, stream>>>(Ha, W1, dinv, Hg, N, 128);
    k_aggregate<32><<<aggN_blocks, 256, 0, stream>>>(Hg, csr, rowstart, dinv, b1, Ha, N, 128);
    hipMemsetAsync(stats, 0, 256 * 4, stream);
    k_bn_stats<<<512, 256, 0, stream>>>(Ha, stats, N);
    k_bn_relu<<<2048, 256, 0, stream>>>(Ha, stats, g1, bt1, N);

    // layer 3 (no BN, no relu)
    k_gemm<<<dim3((N + 63) / 64, (DOUT + 63) / 64), 256, 0, stream>>>(Ha, W2, dinv, Hg, N, DOUT);
    k_aggregate<16><<<aggO_blocks, 256, 0, stream>>>(Hg, csr, rowstart, dinv, b2, out, N, DOUT);
    k_logsoftmax<<<(N + 3) / 4, 256, 0, stream>>>(out, N, DOUT);
}

// Round 3
// 470.898 us; speedup vs baseline: 1.8317x; 1.3033x over previous
//
#include <hip/hip_runtime.h>
#include <cstdint>

// ---------------- graph preprocessing ----------------

__global__ __launch_bounds__(256) void k_count(const int* __restrict__ dst, int* __restrict__ cnt, int E) {
    int e = blockIdx.x * 256 + threadIdx.x;
    if (e < E) atomicAdd(&cnt[dst[e]], 1);
}

__global__ __launch_bounds__(256) void k_dinv(const int* __restrict__ cnt, float* __restrict__ dinv, int N) {
    int i = blockIdx.x * 256 + threadIdx.x;
    if (i < N) dinv[i] = rsqrtf((float)(cnt[i] + 1));   // +1 self-loop
}

// single-block exclusive scan of cnt[N] -> rowstart[N+1]
__global__ __launch_bounds__(1024) void k_scan(const int* __restrict__ cnt, int* __restrict__ rowstart, int N) {
    __shared__ int ls[1024];
    int t = threadIdx.x;
    int chunk = (N + 1023) >> 10;
    int begin = t * chunk; if (begin > N) begin = N;
    int end = begin + chunk; if (end > N) end = N;
    int s = 0;
    for (int i = begin; i < end; i++) s += cnt[i];
    ls[t] = s;
    __syncthreads();
    for (int off = 1; off < 1024; off <<= 1) {
        int o = (t >= off) ? ls[t - off] : 0;
        __syncthreads();
        ls[t] += o;
        __syncthreads();
    }
    int run = ls[t] - s;
    for (int i = begin; i < end; i++) { rowstart[i] = run; run += cnt[i]; }
    if (t == 1023) rowstart[N] = ls[1023];
}

__global__ __launch_bounds__(256) void k_scatter(const int* __restrict__ src, const int* __restrict__ dst,
                                                 const int* __restrict__ rowstart, int* __restrict__ cursor,
                                                 int* __restrict__ csr, int E) {
    int e = blockIdx.x * 256 + threadIdx.x;
    if (e >= E) return;
    int d = dst[e];
    int pos = rowstart[d] + atomicAdd(&cursor[d], 1);
    csr[pos] = src[e];
}

// ---------------- GEMM v2 ----------------
// C[M x NC] = (act(A) @ B) * dscale[row],  act = BN-affine+ReLU if wsh != null.
// Tile 64 rows x 128 cols, 256 threads, microtile 4x8, K=128 in chunks of 32.
// A staged TRANSPOSED in LDS so the 4-row fragment is one ds_read_b128.

__global__ __launch_bounds__(256, 4) void k_gemm2(const float* __restrict__ A, const float* __restrict__ B,
                                                  const float* __restrict__ wsh,     // [0..127]=w, [128..255]=sh; may be null
                                                  const float* __restrict__ dscale,
                                                  float* __restrict__ C, int M, int NC) {
    __shared__ float Ast[32][68];    // [k][row], padded
    __shared__ float Bs[32][128];    // [k][col]
    int t = threadIdx.x;
    int row0 = blockIdx.x * 64;
    int rt = t >> 4;                 // 0..15 -> rows rt*4..+3
    int ct = t & 15;                 // 0..15 -> cols ct*8..+7
    float acc[4][8] = {};

    for (int kt = 0; kt < 128; kt += 32) {
        // ---- stage A (64 rows x 32 k), transposed into Ast[k][row]; 512 float4, 2/thread
#pragma unroll
        for (int ff = 0; ff < 2; ff++) {
            int f = t + ff * 256;
            int row = f >> 3;                  // 0..63
            int k4 = (f & 7) << 2;             // 0..28
            float4 v = make_float4(0.f, 0.f, 0.f, 0.f);
            int grow = row0 + row;
            if (grow < M) {
                v = *(const float4*)(A + (size_t)grow * 128 + kt + k4);
                if (wsh) {
                    float4 w4  = *(const float4*)(wsh + kt + k4);
                    float4 sh4 = *(const float4*)(wsh + 128 + kt + k4);
                    v.x = fmaxf(v.x * w4.x + sh4.x, 0.f);
                    v.y = fmaxf(v.y * w4.y + sh4.y, 0.f);
                    v.z = fmaxf(v.z * w4.z + sh4.z, 0.f);
                    v.w = fmaxf(v.w * w4.w + sh4.w, 0.f);
                }
            }
            Ast[k4 + 0][row] = v.x;
            Ast[k4 + 1][row] = v.y;
            Ast[k4 + 2][row] = v.z;
            Ast[k4 + 3][row] = v.w;
        }
        // ---- stage B (32 k x 128 cols); 1024 float4, 4/thread
#pragma unroll
        for (int ff = 0; ff < 4; ff++) {
            int f = t + ff * 256;
            int k = f >> 5;                    // 0..31
            int c4 = (f & 31) << 2;            // 0..124
            float4 v = make_float4(0.f, 0.f, 0.f, 0.f);
            if (c4 + 3 < NC) {
                v = *(const float4*)(B + (size_t)(kt + k) * NC + c4);
            } else if (c4 < NC) {
                float tmp[4] = {0.f, 0.f, 0.f, 0.f};
                for (int j = 0; j < 4; j++) if (c4 + j < NC) tmp[j] = B[(size_t)(kt + k) * NC + c4 + j];
                v = make_float4(tmp[0], tmp[1], tmp[2], tmp[3]);
            }
            *(float4*)(&Bs[k][c4]) = v;
        }
        __syncthreads();
#pragma unroll 8
        for (int k = 0; k < 32; k++) {
            float4 a  = *(const float4*)(&Ast[k][rt << 2]);
            float4 b0 = *(const float4*)(&Bs[k][ct << 3]);
            float4 b1 = *(const float4*)(&Bs[k][(ct << 3) + 4]);
            float av[4] = {a.x, a.y, a.z, a.w};
            float bv[8] = {b0.x, b0.y, b0.z, b0.w, b1.x, b1.y, b1.z, b1.w};
#pragma unroll
            for (int i = 0; i < 4; i++)
#pragma unroll
                for (int j = 0; j < 8; j++)
                    acc[i][j] = fmaf(av[i], bv[j], acc[i][j]);
        }
        __syncthreads();
    }

    int col = ct << 3;
#pragma unroll
    for (int i = 0; i < 4; i++) {
        int r = row0 + (rt << 2) + i;
        if (r >= M) continue;
        float dn = dscale[r];
        if (col + 7 < NC) {
            float4 v0 = make_float4(acc[i][0] * dn, acc[i][1] * dn, acc[i][2] * dn, acc[i][3] * dn);
            float4 v1 = make_float4(acc[i][4] * dn, acc[i][5] * dn, acc[i][6] * dn, acc[i][7] * dn);
            *(float4*)(C + (size_t)r * NC + col) = v0;
            *(float4*)(C + (size_t)r * NC + col + 4) = v1;
        } else {
            for (int j = 0; j < 8; j++)
                if (col + j < NC) C[(size_t)r * NC + col + j] = acc[i][j] * dn;
        }
    }
}

// ---------------- aggregation ----------------
// Hs rows pre-scaled by dinv[src]. out[n] = (sum_in Hs[s] + Hs[n]) * dinv[n] + b

template<int TPN>
__global__ __launch_bounds__(256) void k_aggregate(const float* __restrict__ Hs, const int* __restrict__ csr,
                                                   const int* __restrict__ rowstart, const float* __restrict__ dinv,
                                                   const float* __restrict__ bias, float* __restrict__ out,
                                                   int N, int D) {
    constexpr int NPB = 256 / TPN;
    int node = blockIdx.x * NPB + threadIdx.x / TPN;
    int lane = threadIdx.x % TPN;
    int c = lane << 2;
    if (node >= N) return;
    bool act = c < D;

    int s0 = rowstart[node], s1 = rowstart[node + 1];
    float ax = 0.f, ay = 0.f, az = 0.f, aw = 0.f;

    int j = s0;
    for (; j + 8 <= s1; j += 8) {
        int i0 = csr[j + 0], i1 = csr[j + 1], i2 = csr[j + 2], i3 = csr[j + 3];
        int i4 = csr[j + 4], i5 = csr[j + 5], i6 = csr[j + 6], i7 = csr[j + 7];
        if (act) {
            float4 v0 = *(const float4*)(Hs + (size_t)i0 * D + c);
            float4 v1 = *(const float4*)(Hs + (size_t)i1 * D + c);
            float4 v2 = *(const float4*)(Hs + (size_t)i2 * D + c);
            float4 v3 = *(const float4*)(Hs + (size_t)i3 * D + c);
            float4 v4 = *(const float4*)(Hs + (size_t)i4 * D + c);
            float4 v5 = *(const float4*)(Hs + (size_t)i5 * D + c);
            float4 v6 = *(const float4*)(Hs + (size_t)i6 * D + c);
            float4 v7 = *(const float4*)(Hs + (size_t)i7 * D + c);
            ax += v0.x; ay += v0.y; az += v0.z; aw += v0.w;
            ax += v1.x; ay += v1.y; az += v1.z; aw += v1.w;
            ax += v2.x; ay += v2.y; az += v2.z; aw += v2.w;
            ax += v3.x; ay += v3.y; az += v3.z; aw += v3.w;
            ax += v4.x; ay += v4.y; az += v4.z; aw += v4.w;
            ax += v5.x; ay += v5.y; az += v5.z; aw += v5.w;
            ax += v6.x; ay += v6.y; az += v6.z; aw += v6.w;
            ax += v7.x; ay += v7.y; az += v7.z; aw += v7.w;
        }
    }
    for (; j < s1; j++) {
        int s = csr[j];
        if (act) {
            float4 v = *(const float4*)(Hs + (size_t)s * D + c);
            ax += v.x; ay += v.y; az += v.z; aw += v.w;
        }
    }

    if (act) {
        float4 self = *(const float4*)(Hs + (size_t)node * D + c);
        float dn = dinv[node];
        float4 b4 = *(const float4*)(bias + c);
        float4 r;
        r.x = (ax + self.x) * dn + b4.x;
        r.y = (ay + self.y) * dn + b4.y;
        r.z = (az + self.z) * dn + b4.z;
        r.w = (aw + self.w) * dn + b4.w;
        *(float4*)(out + (size_t)node * D + c) = r;
    }
}

// ---------------- BatchNorm stats + prep ----------------

__global__ __launch_bounds__(256) void k_bn_stats(const float* __restrict__ H, float* __restrict__ sums, int N) {
    __shared__ float ls[256], ls2[256];
    int c = threadIdx.x & 127;
    int half = threadIdx.x >> 7;
    float s = 0.f, s2 = 0.f;
    for (int r = blockIdx.x * 2 + half; r < N; r += gridDim.x * 2) {
        float v = H[(size_t)r * 128 + c];
        s += v; s2 += v * v;
    }
    ls[threadIdx.x] = s; ls2[threadIdx.x] = s2;
    __syncthreads();
    if (threadIdx.x < 128) {
        atomicAdd(&sums[c], ls[threadIdx.x] + ls[threadIdx.x + 128]);
        atomicAdd(&sums[128 + c], ls2[threadIdx.x] + ls2[threadIdx.x + 128]);
    }
}

// w[c] = rsqrt(var+eps)*g[c]; sh[c] = bt[c] - mu*w[c]   (wsh: [0..127]=w, [128..255]=sh)
__global__ __launch_bounds__(128) void k_bn_prep(const float* __restrict__ sums, const float* __restrict__ g,
                                                 const float* __restrict__ bt, float* __restrict__ wsh, int N) {
    int c = threadIdx.x;
    float invN = 1.0f / (float)N;
    float mu = sums[c] * invN;
    float var = sums[128 + c] * invN - mu * mu;
    float w = rsqrtf(var + 1e-5f) * g[c];
    wsh[c] = w;
    wsh[128 + c] = bt[c] - mu * w;
}

// ---------------- log_softmax over rows of D (<=64) ----------------

__global__ __launch_bounds__(256) void k_logsoftmax(float* __restrict__ out, int N, int D) {
    int wid = threadIdx.x >> 6;
    int lane = threadIdx.x & 63;
    int row = blockIdx.x * 4 + wid;
    if (row >= N) return;
    float v = (lane < D) ? out[(size_t)row * D + lane] : -1e30f;
    float m = v;
#pragma unroll
    for (int off = 32; off; off >>= 1) m = fmaxf(m, __shfl_xor(m, off, 64));
    float e = (lane < D) ? expf(v - m) : 0.f;
    float s = e;
#pragma unroll
    for (int off = 32; off; off >>= 1) s += __shfl_xor(s, off, 64);
    if (lane < D) out[(size_t)row * D + lane] = (v - m) - logf(s);
}

// ---------------- launch ----------------

extern "C" void kernel_launch(void* const* d_in, const int* in_sizes, int n_in,
                              void* d_out, int out_size, void* d_ws, size_t ws_size,
                              hipStream_t stream) {
    const float* x   = (const float*)d_in[0];
    const int*   ei  = (const int*)d_in[1];
    const float* W0  = (const float*)d_in[2];
    const float* b0  = (const float*)d_in[3];
    const float* W1  = (const float*)d_in[4];
    const float* b1  = (const float*)d_in[5];
    const float* W2  = (const float*)d_in[6];
    const float* b2  = (const float*)d_in[7];
    const float* g0  = (const float*)d_in[8];
    const float* bt0 = (const float*)d_in[9];
    const float* g1  = (const float*)d_in[10];
    const float* bt1 = (const float*)d_in[11];
    float* out = (float*)d_out;

    int N    = in_sizes[0] / 128;
    int E    = in_sizes[1] / 2;
    int DOUT = in_sizes[7];

    const int* srcp = ei;
    const int* dstp = ei + E;

    size_t off = 0;
    auto carve = [&](size_t bytes) { size_t o = off; off += (bytes + 255) & ~(size_t)255; return (char*)d_ws + o; };
    int*   cnt      = (int*)carve((size_t)N * 4);
    int*   rowstart = (int*)carve((size_t)(N + 1) * 4);
    int*   cursor   = (int*)carve((size_t)N * 4);
    int*   csr      = (int*)carve((size_t)E * 4);
    float* dinv     = (float*)carve((size_t)N * 4);
    float* stats    = (float*)carve(256 * 4);
    float* wsh0     = (float*)carve(256 * 4);
    float* wsh1     = (float*)carve(256 * 4);
    float* Hg       = (float*)carve((size_t)N * 128 * 4);
    float* Ha       = (float*)carve((size_t)N * 128 * 4);

    hipMemsetAsync(cnt, 0, (size_t)N * 4, stream);
    hipMemsetAsync(cursor, 0, (size_t)N * 4, stream);

    k_count<<<(E + 255) / 256, 256, 0, stream>>>(dstp, cnt, E);
    k_dinv<<<(N + 255) / 256, 256, 0, stream>>>(cnt, dinv, N);
    k_scan<<<1, 1024, 0, stream>>>(cnt, rowstart, N);
    k_scatter<<<(E + 255) / 256, 256, 0, stream>>>(srcp, dstp, rowstart, cursor, csr, E);

    int gemm_blocks = (N + 63) / 64;
    int aggN_blocks = (N + 7) / 8;     // TPN=32
    int aggO_blocks = (N + 15) / 16;   // TPN=16

    // layer 1: conv -> stats -> prep (BN+ReLU applied inside next GEMM's A-load)
    k_gemm2<<<gemm_blocks, 256, 0, stream>>>(x, W0, nullptr, dinv, Hg, N, 128);
    k_aggregate<32><<<aggN_blocks, 256, 0, stream>>>(Hg, csr, rowstart, dinv, b0, Ha, N, 128);
    hipMemsetAsync(stats, 0, 256 * 4, stream);
    k_bn_stats<<<512, 256, 0, stream>>>(Ha, stats, N);
    k_bn_prep<<<1, 128, 0, stream>>>(stats, g0, bt0, wsh0, N);

    // layer 2
    k_gemm2<<<gemm_blocks, 256, 0, stream>>>(Ha, W1, wsh0, dinv, Hg, N, 128);
    k_aggregate<32><<<aggN_blocks, 256, 0, stream>>>(Hg, csr, rowstart, dinv, b1, Ha, N, 128);
    hipMemsetAsync(stats, 0, 256 * 4, stream);
    k_bn_stats<<<512, 256, 0, stream>>>(Ha, stats, N);
    k_bn_prep<<<1, 128, 0, stream>>>(stats, g1, bt1, wsh1, N);

    // layer 3 (BN+ReLU of layer 2 fused into A-load; no BN after)
    k_gemm2<<<gemm_blocks, 256, 0, stream>>>(Ha, W2, wsh1, dinv, Hg, N, DOUT);
    k_aggregate<16><<<aggO_blocks, 256, 0, stream>>>(Hg, csr, rowstart, dinv, b2, out, N, DOUT);
    k_logsoftmax<<<(N + 3) / 4, 256, 0, stream>>>(out, N, DOUT);
}

// Round 4
// 400.871 us; speedup vs baseline: 2.1516x; 1.1747x over previous
//
#include <hip/hip_runtime.h>
#include <cstdint>

// ---------------- graph preprocessing ----------------

__global__ __launch_bounds__(256) void k_count(const int* __restrict__ dst, int* __restrict__ cnt, int E) {
    int e = blockIdx.x * 256 + threadIdx.x;
    if (e < E) atomicAdd(&cnt[dst[e]], 1);
}

__global__ __launch_bounds__(256) void k_dinv(const int* __restrict__ cnt, float* __restrict__ dinv, int N) {
    int i = blockIdx.x * 256 + threadIdx.x;
    if (i < N) dinv[i] = rsqrtf((float)(cnt[i] + 1));   // +1 self-loop
}

// ---- hierarchical exclusive scan: cnt[N] -> rowstart[N+1], 4096 elems/block ----

__global__ __launch_bounds__(256) void k_scan_sum(const int* __restrict__ cnt, int* __restrict__ bsum, int N) {
    int base = blockIdx.x * 4096 + threadIdx.x * 16;
    int s = 0;
    if (base + 16 <= N) {
        const int4* p = (const int4*)(cnt + base);
        int4 a = p[0], b = p[1], c = p[2], d = p[3];
        s = a.x + a.y + a.z + a.w + b.x + b.y + b.z + b.w
          + c.x + c.y + c.z + c.w + d.x + d.y + d.z + d.w;
    } else {
        for (int i = base; i < N; i++) s += cnt[i];
    }
    __shared__ int ws[4];
#pragma unroll
    for (int off = 32; off; off >>= 1) s += __shfl_down(s, off, 64);
    if ((threadIdx.x & 63) == 0) ws[threadIdx.x >> 6] = s;
    __syncthreads();
    if (threadIdx.x == 0) bsum[blockIdx.x] = ws[0] + ws[1] + ws[2] + ws[3];
}

__global__ void k_scan_top(const int* __restrict__ bsum, int* __restrict__ boff,
                           int* __restrict__ rowstartN, int B) {
    if (threadIdx.x == 0) {
        int run = 0;
        for (int b = 0; b < B; b++) { boff[b] = run; run += bsum[b]; }
        *rowstartN = run;
    }
}

__global__ __launch_bounds__(256) void k_scan_apply(const int* __restrict__ cnt, const int* __restrict__ boff,
                                                    int* __restrict__ rowstart, int N) {
    int t = threadIdx.x;
    int base = blockIdx.x * 4096 + t * 16;
    int v[16];
    int s = 0;
    if (base + 16 <= N) {
        const int4* p = (const int4*)(cnt + base);
        int4 q0 = p[0], q1 = p[1], q2 = p[2], q3 = p[3];
        int e[16] = {q0.x, q0.y, q0.z, q0.w, q1.x, q1.y, q1.z, q1.w,
                     q2.x, q2.y, q2.z, q2.w, q3.x, q3.y, q3.z, q3.w};
#pragma unroll
        for (int j = 0; j < 16; j++) { v[j] = s; s += e[j]; }
    } else {
#pragma unroll
        for (int j = 0; j < 16; j++) { int i = base + j; int x = (i < N) ? cnt[i] : 0; v[j] = s; s += x; }
    }
    __shared__ int ls[256];
    ls[t] = s;
    __syncthreads();
    for (int off = 1; off < 256; off <<= 1) {
        int o = (t >= off) ? ls[t - off] : 0;
        __syncthreads();
        ls[t] += o;
        __syncthreads();
    }
    int excl = ls[t] - s + boff[blockIdx.x];
    if (base + 16 <= N) {
        int w[16];
#pragma unroll
        for (int j = 0; j < 16; j++) w[j] = v[j] + excl;
        int4* p = (int4*)(rowstart + base);
        p[0] = make_int4(w[0], w[1], w[2], w[3]);
        p[1] = make_int4(w[4], w[5], w[6], w[7]);
        p[2] = make_int4(w[8], w[9], w[10], w[11]);
        p[3] = make_int4(w[12], w[13], w[14], w[15]);
    } else {
        for (int j = 0; j < 16; j++) { int i = base + j; if (i < N) rowstart[i] = v[j] + excl; }
    }
}

__global__ __launch_bounds__(256) void k_scatter(const int* __restrict__ src, const int* __restrict__ dst,
                                                 const int* __restrict__ rowstart, int* __restrict__ cursor,
                                                 int* __restrict__ csr, int E) {
    int e = blockIdx.x * 256 + threadIdx.x;
    if (e >= E) return;
    int d = dst[e];
    int pos = rowstart[d] + atomicAdd(&cursor[d], 1);
    csr[pos] = src[e];
}

// ---------------- GEMM v3 ----------------
// C[M x NC] = (act(A) @ B) * dscale[row],  act = BN-affine+ReLU if wsh != null.
// Tile 64 rows x 128 cols, 256 threads, microtile 4x(4+4) (cols ct*4 and 64+ct*4
// -> 2-way LDS banks = free). K=128 in chunks of 32, register-prefetch double buffer.

__global__ __launch_bounds__(256, 4) void k_gemm2(const float* __restrict__ A, const float* __restrict__ B,
                                                  const float* __restrict__ wsh,     // [0..127]=w, [128..255]=sh; may be null
                                                  const float* __restrict__ dscale,
                                                  float* __restrict__ C, int M, int NC) {
    __shared__ float Ast[32][68];    // [k][row], padded
    __shared__ float Bs[32][128];    // [k][col]
    int t = threadIdx.x;
    int row0 = blockIdx.x * 64;
    int rt = t >> 4;                 // 0..15 -> rows rt*4..+3
    int ct = t & 15;                 // 0..15 -> cols {ct*4..+3, 64+ct*4..+3}
    float acc[4][8] = {};

    // per-thread staging coordinates
    int fa0 = t, fa1 = t + 256;                  // A: f>>3 = row, (f&7)<<2 = k4
    int ar0 = fa0 >> 3, ak0 = (fa0 & 7) << 2;
    int ar1 = fa1 >> 3, ak1 = (fa1 & 7) << 2;

    float4 pa[2], pw[2], psh[2], pb[4];
    bool use_wsh = (wsh != nullptr);

    auto prefetch = [&](int kt) {
        int grow0 = row0 + ar0, grow1 = row0 + ar1;
        pa[0] = make_float4(0.f, 0.f, 0.f, 0.f);
        pa[1] = make_float4(0.f, 0.f, 0.f, 0.f);
        if (grow0 < M) pa[0] = *(const float4*)(A + (size_t)grow0 * 128 + kt + ak0);
        if (grow1 < M) pa[1] = *(const float4*)(A + (size_t)grow1 * 128 + kt + ak1);
        if (use_wsh) {
            pw[0]  = *(const float4*)(wsh + kt + ak0);
            psh[0] = *(const float4*)(wsh + 128 + kt + ak0);
            pw[1]  = *(const float4*)(wsh + kt + ak1);
            psh[1] = *(const float4*)(wsh + 128 + kt + ak1);
        }
#pragma unroll
        for (int ff = 0; ff < 4; ff++) {
            int f = t + ff * 256;
            int k = f >> 5, c4 = (f & 31) << 2;
            float4 v = make_float4(0.f, 0.f, 0.f, 0.f);
            if (c4 + 3 < NC) {
                v = *(const float4*)(B + (size_t)(kt + k) * NC + c4);
            } else if (c4 < NC) {
                float tmp[4] = {0.f, 0.f, 0.f, 0.f};
                for (int j = 0; j < 4; j++) if (c4 + j < NC) tmp[j] = B[(size_t)(kt + k) * NC + c4 + j];
                v = make_float4(tmp[0], tmp[1], tmp[2], tmp[3]);
            }
            pb[ff] = v;
        }
    };

    prefetch(0);

    for (int kt = 0; kt < 128; kt += 32) {
        // ---- write staged regs to LDS (transform A on the way in)
#pragma unroll
        for (int s = 0; s < 2; s++) {
            float4 v = pa[s];
            if (use_wsh) {
                float4 w4 = pw[s], sh4 = psh[s];
                v.x = fmaxf(fmaf(v.x, w4.x, sh4.x), 0.f);
                v.y = fmaxf(fmaf(v.y, w4.y, sh4.y), 0.f);
                v.z = fmaxf(fmaf(v.z, w4.z, sh4.z), 0.f);
                v.w = fmaxf(fmaf(v.w, w4.w, sh4.w), 0.f);
            }
            int row = s ? ar1 : ar0, k4 = s ? ak1 : ak0;
            Ast[k4 + 0][row] = v.x;
            Ast[k4 + 1][row] = v.y;
            Ast[k4 + 2][row] = v.z;
            Ast[k4 + 3][row] = v.w;
        }
#pragma unroll
        for (int ff = 0; ff < 4; ff++) {
            int f = t + ff * 256;
            int k = f >> 5, c4 = (f & 31) << 2;
            *(float4*)(&Bs[k][c4]) = pb[ff];
        }
        __syncthreads();

        if (kt + 32 < 128) prefetch(kt + 32);   // overlaps with compute below

#pragma unroll 8
        for (int k = 0; k < 32; k++) {
            float4 a  = *(const float4*)(&Ast[k][rt << 2]);
            float4 b0 = *(const float4*)(&Bs[k][ct << 2]);
            float4 b1 = *(const float4*)(&Bs[k][64 + (ct << 2)]);
            float av[4] = {a.x, a.y, a.z, a.w};
            float bv[8] = {b0.x, b0.y, b0.z, b0.w, b1.x, b1.y, b1.z, b1.w};
#pragma unroll
            for (int i = 0; i < 4; i++)
#pragma unroll
                for (int j = 0; j < 8; j++)
                    acc[i][j] = fmaf(av[i], bv[j], acc[i][j]);
        }
        __syncthreads();
    }

    int colA = ct << 2;          // first 4 cols
    int colB = 64 + (ct << 2);   // second 4 cols
#pragma unroll
    for (int i = 0; i < 4; i++) {
        int r = row0 + (rt << 2) + i;
        if (r >= M) continue;
        float dn = dscale[r];
        if (colA + 3 < NC) {
            float4 v0 = make_float4(acc[i][0] * dn, acc[i][1] * dn, acc[i][2] * dn, acc[i][3] * dn);
            *(float4*)(C + (size_t)r * NC + colA) = v0;
        } else {
            for (int j = 0; j < 4; j++)
                if (colA + j < NC) C[(size_t)r * NC + colA + j] = acc[i][j] * dn;
        }
        if (colB + 3 < NC) {
            float4 v1 = make_float4(acc[i][4] * dn, acc[i][5] * dn, acc[i][6] * dn, acc[i][7] * dn);
            *(float4*)(C + (size_t)r * NC + colB) = v1;
        } else {
            for (int j = 0; j < 4; j++)
                if (colB + j < NC) C[(size_t)r * NC + colB + j] = acc[i][4 + j] * dn;
        }
    }
}

// ---------------- aggregation ----------------
// Hs rows pre-scaled by dinv[src]. out[n] = (sum_in Hs[s] + Hs[n]) * dinv[n] + b

template<int TPN>
__global__ __launch_bounds__(256) void k_aggregate(const float* __restrict__ Hs, const int* __restrict__ csr,
                                                   const int* __restrict__ rowstart, const float* __restrict__ dinv,
                                                   const float* __restrict__ bias, float* __restrict__ out,
                                                   int N, int D) {
    constexpr int NPB = 256 / TPN;
    int node = blockIdx.x * NPB + threadIdx.x / TPN;
    int lane = threadIdx.x % TPN;
    int c = lane << 2;
    if (node >= N) return;
    bool act = c < D;

    int s0 = rowstart[node], s1 = rowstart[node + 1];
    float ax = 0.f, ay = 0.f, az = 0.f, aw = 0.f;

    int j = s0;
    for (; j + 8 <= s1; j += 8) {
        int i0 = csr[j + 0], i1 = csr[j + 1], i2 = csr[j + 2], i3 = csr[j + 3];
        int i4 = csr[j + 4], i5 = csr[j + 5], i6 = csr[j + 6], i7 = csr[j + 7];
        if (act) {
            float4 v0 = *(const float4*)(Hs + (size_t)i0 * D + c);
            float4 v1 = *(const float4*)(Hs + (size_t)i1 * D + c);
            float4 v2 = *(const float4*)(Hs + (size_t)i2 * D + c);
            float4 v3 = *(const float4*)(Hs + (size_t)i3 * D + c);
            float4 v4 = *(const float4*)(Hs + (size_t)i4 * D + c);
            float4 v5 = *(const float4*)(Hs + (size_t)i5 * D + c);
            float4 v6 = *(const float4*)(Hs + (size_t)i6 * D + c);
            float4 v7 = *(const float4*)(Hs + (size_t)i7 * D + c);
            ax += v0.x; ay += v0.y; az += v0.z; aw += v0.w;
            ax += v1.x; ay += v1.y; az += v1.z; aw += v1.w;
            ax += v2.x; ay += v2.y; az += v2.z; aw += v2.w;
            ax += v3.x; ay += v3.y; az += v3.z; aw += v3.w;
            ax += v4.x; ay += v4.y; az += v4.z; aw += v4.w;
            ax += v5.x; ay += v5.y; az += v5.z; aw += v5.w;
            ax += v6.x; ay += v6.y; az += v6.z; aw += v6.w;
            ax += v7.x; ay += v7.y; az += v7.z; aw += v7.w;
        }
    }
    for (; j < s1; j++) {
        int s = csr[j];
        if (act) {
            float4 v = *(const float4*)(Hs + (size_t)s * D + c);
            ax += v.x; ay += v.y; az += v.z; aw += v.w;
        }
    }

    if (act) {
        float4 self = *(const float4*)(Hs + (size_t)node * D + c);
        float dn = dinv[node];
        float4 b4 = *(const float4*)(bias + c);
        float4 r;
        r.x = (ax + self.x) * dn + b4.x;
        r.y = (ay + self.y) * dn + b4.y;
        r.z = (az + self.z) * dn + b4.z;
        r.w = (aw + self.w) * dn + b4.w;
        *(float4*)(out + (size_t)node * D + c) = r;
    }
}

// ---------------- BatchNorm stats + prep ----------------

__global__ __launch_bounds__(256) void k_bn_stats(const float* __restrict__ H, float* __restrict__ sums, int N) {
    __shared__ float ls[256], ls2[256];
    int c = threadIdx.x & 127;
    int half = threadIdx.x >> 7;
    float s = 0.f, s2 = 0.f;
    for (int r = blockIdx.x * 2 + half; r < N; r += gridDim.x * 2) {
        float v = H[(size_t)r * 128 + c];
        s += v; s2 += v * v;
    }
    ls[threadIdx.x] = s; ls2[threadIdx.x] = s2;
    __syncthreads();
    if (threadIdx.x < 128) {
        atomicAdd(&sums[c], ls[threadIdx.x] + ls[threadIdx.x + 128]);
        atomicAdd(&sums[128 + c], ls2[threadIdx.x] + ls2[threadIdx.x + 128]);
    }
}

// w[c] = rsqrt(var+eps)*g[c]; sh[c] = bt[c] - mu*w[c]
__global__ __launch_bounds__(128) void k_bn_prep(const float* __restrict__ sums, const float* __restrict__ g,
                                                 const float* __restrict__ bt, float* __restrict__ wsh, int N) {
    int c = threadIdx.x;
    float invN = 1.0f / (float)N;
    float mu = sums[c] * invN;
    float var = sums[128 + c] * invN - mu * mu;
    float w = rsqrtf(var + 1e-5f) * g[c];
    wsh[c] = w;
    wsh[128 + c] = bt[c] - mu * w;
}

// ---------------- log_softmax over rows of D (<=64) ----------------

__global__ __launch_bounds__(256) void k_logsoftmax(float* __restrict__ out, int N, int D) {
    int wid = threadIdx.x >> 6;
    int lane = threadIdx.x & 63;
    int row = blockIdx.x * 4 + wid;
    if (row >= N) return;
    float v = (lane < D) ? out[(size_t)row * D + lane] : -1e30f;
    float m = v;
#pragma unroll
    for (int off = 32; off; off >>= 1) m = fmaxf(m, __shfl_xor(m, off, 64));
    float e = (lane < D) ? expf(v - m) : 0.f;
    float s = e;
#pragma unroll
    for (int off = 32; off; off >>= 1) s += __shfl_xor(s, off, 64);
    if (lane < D) out[(size_t)row * D + lane] = (v - m) - logf(s);
}

// ---------------- launch ----------------

extern "C" void kernel_launch(void* const* d_in, const int* in_sizes, int n_in,
                              void* d_out, int out_size, void* d_ws, size_t ws_size,
                              hipStream_t stream) {
    const float* x   = (const float*)d_in[0];
    const int*   ei  = (const int*)d_in[1];
    const float* W0  = (const float*)d_in[2];
    const float* b0  = (const float*)d_in[3];
    const float* W1  = (const float*)d_in[4];
    const float* b1  = (const float*)d_in[5];
    const float* W2  = (const float*)d_in[6];
    const float* b2  = (const float*)d_in[7];
    const float* g0  = (const float*)d_in[8];
    const float* bt0 = (const float*)d_in[9];
    const float* g1  = (const float*)d_in[10];
    const float* bt1 = (const float*)d_in[11];
    float* out = (float*)d_out;

    int N    = in_sizes[0] / 128;
    int E    = in_sizes[1] / 2;
    int DOUT = in_sizes[7];

    const int* srcp = ei;
    const int* dstp = ei + E;

    size_t off = 0;
    auto carve = [&](size_t bytes) { size_t o = off; off += (bytes + 255) & ~(size_t)255; return (char*)d_ws + o; };
    int*   cnt      = (int*)carve((size_t)N * 4);
    int*   rowstart = (int*)carve((size_t)(N + 1) * 4);
    int*   cursor   = (int*)carve((size_t)N * 4);
    int*   csr      = (int*)carve((size_t)E * 4);
    float* dinv     = (float*)carve((size_t)N * 4);
    float* stats    = (float*)carve(256 * 4);
    float* wsh0     = (float*)carve(256 * 4);
    float* wsh1     = (float*)carve(256 * 4);
    int*   bsum     = (int*)carve(64 * 4);
    int*   boff     = (int*)carve(64 * 4);
    float* Hg       = (float*)carve((size_t)N * 128 * 4);
    float* Ha       = (float*)carve((size_t)N * 128 * 4);

    hipMemsetAsync(cnt, 0, (size_t)N * 4, stream);
    hipMemsetAsync(cursor, 0, (size_t)N * 4, stream);

    int SB = (N + 4095) / 4096;   // scan blocks

    k_count<<<(E + 255) / 256, 256, 0, stream>>>(dstp, cnt, E);
    k_dinv<<<(N + 255) / 256, 256, 0, stream>>>(cnt, dinv, N);
    k_scan_sum<<<SB, 256, 0, stream>>>(cnt, bsum, N);
    k_scan_top<<<1, 64, 0, stream>>>(bsum, boff, rowstart + N, SB);
    k_scan_apply<<<SB, 256, 0, stream>>>(cnt, boff, rowstart, N);
    k_scatter<<<(E + 255) / 256, 256, 0, stream>>>(srcp, dstp, rowstart, cursor, csr, E);

    int gemm_blocks = (N + 63) / 64;
    int aggN_blocks = (N + 7) / 8;     // TPN=32
    int aggO_blocks = (N + 15) / 16;   // TPN=16

    // layer 1 (BN+ReLU applied inside next GEMM's A-load)
    k_gemm2<<<gemm_blocks, 256, 0, stream>>>(x, W0, nullptr, dinv, Hg, N, 128);
    k_aggregate<32><<<aggN_blocks, 256, 0, stream>>>(Hg, csr, rowstart, dinv, b0, Ha, N, 128);
    hipMemsetAsync(stats, 0, 256 * 4, stream);
    k_bn_stats<<<512, 256, 0, stream>>>(Ha, stats, N);
    k_bn_prep<<<1, 128, 0, stream>>>(stats, g0, bt0, wsh0, N);

    // layer 2
    k_gemm2<<<gemm_blocks, 256, 0, stream>>>(Ha, W1, wsh0, dinv, Hg, N, 128);
    k_aggregate<32><<<aggN_blocks, 256, 0, stream>>>(Hg, csr, rowstart, dinv, b1, Ha, N, 128);
    hipMemsetAsync(stats, 0, 256 * 4, stream);
    k_bn_stats<<<512, 256, 0, stream>>>(Ha, stats, N);
    k_bn_prep<<<1, 128, 0, stream>>>(stats, g1, bt1, wsh1, N);

    // layer 3
    k_gemm2<<<gemm_blocks, 256, 0, stream>>>(Ha, W2, wsh1, dinv, Hg, N, DOUT);
    k_aggregate<16><<<aggO_blocks, 256, 0, stream>>>(Hg, csr, rowstart, dinv, b2, out, N, DOUT);
    k_logsoftmax<<<(N + 3) / 4, 256, 0, stream>>>(out, N, DOUT);
}

// Round 5
// 349.857 us; speedup vs baseline: 2.4654x; 1.1458x over previous
//
#include <hip/hip_runtime.h>
#include <hip/hip_fp16.h>
#include <cstdint>

// ---------------- graph preprocessing ----------------

__global__ __launch_bounds__(256) void k_count(const int* __restrict__ dst, int* __restrict__ cnt, int E) {
    int e = blockIdx.x * 256 + threadIdx.x;
    if (e < E) atomicAdd(&cnt[dst[e]], 1);
}

__global__ __launch_bounds__(256) void k_dinv(const int* __restrict__ cnt, float* __restrict__ dinv, int N) {
    int i = blockIdx.x * 256 + threadIdx.x;
    if (i < N) dinv[i] = rsqrtf((float)(cnt[i] + 1));   // +1 self-loop
}

// ---- hierarchical exclusive scan: cnt[N] -> rowstart[N+1], 4096 elems/block ----

__global__ __launch_bounds__(256) void k_scan_sum(const int* __restrict__ cnt, int* __restrict__ bsum, int N) {
    int base = blockIdx.x * 4096 + threadIdx.x * 16;
    int s = 0;
    if (base + 16 <= N) {
        const int4* p = (const int4*)(cnt + base);
        int4 a = p[0], b = p[1], c = p[2], d = p[3];
        s = a.x + a.y + a.z + a.w + b.x + b.y + b.z + b.w
          + c.x + c.y + c.z + c.w + d.x + d.y + d.z + d.w;
    } else {
        for (int i = base; i < N; i++) s += cnt[i];
    }
    __shared__ int ws[4];
#pragma unroll
    for (int off = 32; off; off >>= 1) s += __shfl_down(s, off, 64);
    if ((threadIdx.x & 63) == 0) ws[threadIdx.x >> 6] = s;
    __syncthreads();
    if (threadIdx.x == 0) bsum[blockIdx.x] = ws[0] + ws[1] + ws[2] + ws[3];
}

__global__ void k_scan_top(const int* __restrict__ bsum, int* __restrict__ boff,
                           int* __restrict__ rowstartN, int B) {
    if (threadIdx.x == 0) {
        int run = 0;
        for (int b = 0; b < B; b++) { boff[b] = run; run += bsum[b]; }
        *rowstartN = run;
    }
}

__global__ __launch_bounds__(256) void k_scan_apply(const int* __restrict__ cnt, const int* __restrict__ boff,
                                                    int* __restrict__ rowstart, int N) {
    int t = threadIdx.x;
    int base = blockIdx.x * 4096 + t * 16;
    int v[16];
    int s = 0;
    if (base + 16 <= N) {
        const int4* p = (const int4*)(cnt + base);
        int4 q0 = p[0], q1 = p[1], q2 = p[2], q3 = p[3];
        int e[16] = {q0.x, q0.y, q0.z, q0.w, q1.x, q1.y, q1.z, q1.w,
                     q2.x, q2.y, q2.z, q2.w, q3.x, q3.y, q3.z, q3.w};
#pragma unroll
        for (int j = 0; j < 16; j++) { v[j] = s; s += e[j]; }
    } else {
#pragma unroll
        for (int j = 0; j < 16; j++) { int i = base + j; int x = (i < N) ? cnt[i] : 0; v[j] = s; s += x; }
    }
    __shared__ int ls[256];
    ls[t] = s;
    __syncthreads();
    for (int off = 1; off < 256; off <<= 1) {
        int o = (t >= off) ? ls[t - off] : 0;
        __syncthreads();
        ls[t] += o;
        __syncthreads();
    }
    int excl = ls[t] - s + boff[blockIdx.x];
    if (base + 16 <= N) {
        int w[16];
#pragma unroll
        for (int j = 0; j < 16; j++) w[j] = v[j] + excl;
        int4* p = (int4*)(rowstart + base);
        p[0] = make_int4(w[0], w[1], w[2], w[3]);
        p[1] = make_int4(w[4], w[5], w[6], w[7]);
        p[2] = make_int4(w[8], w[9], w[10], w[11]);
        p[3] = make_int4(w[12], w[13], w[14], w[15]);
    } else {
        for (int j = 0; j < 16; j++) { int i = base + j; if (i < N) rowstart[i] = v[j] + excl; }
    }
}

__global__ __launch_bounds__(256) void k_scatter(const int* __restrict__ src, const int* __restrict__ dst,
                                                 const int* __restrict__ rowstart, int* __restrict__ cursor,
                                                 int* __restrict__ csr, int E) {
    int e = blockIdx.x * 256 + threadIdx.x;
    if (e >= E) return;
    int d = dst[e];
    int pos = rowstart[d] + atomicAdd(&cursor[d], 1);
    csr[pos] = src[e];
}

// ---------------- typed stores ----------------

__device__ inline void store4f(float* p, float4 v) { *(float4*)p = v; }
__device__ inline void store4f(__half* p, float4 v) {
    union { __half2 h[2]; float2 f; } u;
    u.h[0] = __floats2half2_rn(v.x, v.y);
    u.h[1] = __floats2half2_rn(v.z, v.w);
    *(float2*)p = u.f;   // one 8B store
}
__device__ inline void store1f(float* p, float v) { *p = v; }
__device__ inline void store1f(__half* p, float v) { *p = __float2half(v); }

// ---------------- GEMM ----------------
// C[M x NC] = (act(A) @ B) * dscale[row],  act = BN-affine+ReLU if wsh != null.
// Tile 64 rows x 128 cols, 256 threads, microtile 4x(4+4), K=128 in chunks of 32,
// register-prefetch double buffer. OutT = float or __half.

template<typename OutT>
__global__ __launch_bounds__(256, 4) void k_gemm2(const float* __restrict__ A, const float* __restrict__ B,
                                                  const float* __restrict__ wsh,
                                                  const float* __restrict__ dscale,
                                                  OutT* __restrict__ C, int M, int NC) {
    __shared__ float Ast[32][68];    // [k][row], padded
    __shared__ float Bs[32][128];    // [k][col]
    int t = threadIdx.x;
    int row0 = blockIdx.x * 64;
    int rt = t >> 4;                 // 0..15 -> rows rt*4..+3
    int ct = t & 15;                 // 0..15 -> cols {ct*4..+3, 64+ct*4..+3}
    float acc[4][8] = {};

    int fa0 = t, fa1 = t + 256;
    int ar0 = fa0 >> 3, ak0 = (fa0 & 7) << 2;
    int ar1 = fa1 >> 3, ak1 = (fa1 & 7) << 2;

    float4 pa[2], pw[2], psh[2], pb[4];
    bool use_wsh = (wsh != nullptr);

    auto prefetch = [&](int kt) {
        int grow0 = row0 + ar0, grow1 = row0 + ar1;
        pa[0] = make_float4(0.f, 0.f, 0.f, 0.f);
        pa[1] = make_float4(0.f, 0.f, 0.f, 0.f);
        if (grow0 < M) pa[0] = *(const float4*)(A + (size_t)grow0 * 128 + kt + ak0);
        if (grow1 < M) pa[1] = *(const float4*)(A + (size_t)grow1 * 128 + kt + ak1);
        if (use_wsh) {
            pw[0]  = *(const float4*)(wsh + kt + ak0);
            psh[0] = *(const float4*)(wsh + 128 + kt + ak0);
            pw[1]  = *(const float4*)(wsh + kt + ak1);
            psh[1] = *(const float4*)(wsh + 128 + kt + ak1);
        }
#pragma unroll
        for (int ff = 0; ff < 4; ff++) {
            int f = t + ff * 256;
            int k = f >> 5, c4 = (f & 31) << 2;
            float4 v = make_float4(0.f, 0.f, 0.f, 0.f);
            if (c4 + 3 < NC) {
                v = *(const float4*)(B + (size_t)(kt + k) * NC + c4);
            } else if (c4 < NC) {
                float tmp[4] = {0.f, 0.f, 0.f, 0.f};
                for (int j = 0; j < 4; j++) if (c4 + j < NC) tmp[j] = B[(size_t)(kt + k) * NC + c4 + j];
                v = make_float4(tmp[0], tmp[1], tmp[2], tmp[3]);
            }
            pb[ff] = v;
        }
    };

    prefetch(0);

    for (int kt = 0; kt < 128; kt += 32) {
#pragma unroll
        for (int s = 0; s < 2; s++) {
            float4 v = pa[s];
            if (use_wsh) {
                float4 w4 = pw[s], sh4 = psh[s];
                v.x = fmaxf(fmaf(v.x, w4.x, sh4.x), 0.f);
                v.y = fmaxf(fmaf(v.y, w4.y, sh4.y), 0.f);
                v.z = fmaxf(fmaf(v.z, w4.z, sh4.z), 0.f);
                v.w = fmaxf(fmaf(v.w, w4.w, sh4.w), 0.f);
            }
            int row = s ? ar1 : ar0, k4 = s ? ak1 : ak0;
            Ast[k4 + 0][row] = v.x;
            Ast[k4 + 1][row] = v.y;
            Ast[k4 + 2][row] = v.z;
            Ast[k4 + 3][row] = v.w;
        }
#pragma unroll
        for (int ff = 0; ff < 4; ff++) {
            int f = t + ff * 256;
            int k = f >> 5, c4 = (f & 31) << 2;
            *(float4*)(&Bs[k][c4]) = pb[ff];
        }
        __syncthreads();

        if (kt + 32 < 128) prefetch(kt + 32);

#pragma unroll 8
        for (int k = 0; k < 32; k++) {
            float4 a  = *(const float4*)(&Ast[k][rt << 2]);
            float4 b0 = *(const float4*)(&Bs[k][ct << 2]);
            float4 b1 = *(const float4*)(&Bs[k][64 + (ct << 2)]);
            float av[4] = {a.x, a.y, a.z, a.w};
            float bv[8] = {b0.x, b0.y, b0.z, b0.w, b1.x, b1.y, b1.z, b1.w};
#pragma unroll
            for (int i = 0; i < 4; i++)
#pragma unroll
                for (int j = 0; j < 8; j++)
                    acc[i][j] = fmaf(av[i], bv[j], acc[i][j]);
        }
        __syncthreads();
    }

    int colA = ct << 2;
    int colB = 64 + (ct << 2);
#pragma unroll
    for (int i = 0; i < 4; i++) {
        int r = row0 + (rt << 2) + i;
        if (r >= M) continue;
        float dn = dscale[r];
        if (colA + 3 < NC) {
            store4f(C + (size_t)r * NC + colA,
                    make_float4(acc[i][0] * dn, acc[i][1] * dn, acc[i][2] * dn, acc[i][3] * dn));
        } else {
            for (int j = 0; j < 4; j++)
                if (colA + j < NC) store1f(C + (size_t)r * NC + colA + j, acc[i][j] * dn);
        }
        if (colB + 3 < NC) {
            store4f(C + (size_t)r * NC + colB,
                    make_float4(acc[i][4] * dn, acc[i][5] * dn, acc[i][6] * dn, acc[i][7] * dn));
        } else {
            for (int j = 0; j < 4; j++)
                if (colB + j < NC) store1f(C + (size_t)r * NC + colB + j, acc[i][4 + j] * dn);
        }
    }
}

// ---------------- aggregation, fp16 gather (D=128) ----------------
// Hs rows pre-scaled by dinv[src], stored fp16. out fp32.
// 32 threads/node, 4 channels (8B) per lane, edge loop unrolled 8x.

__device__ inline void acc_h4(float2 raw, float& ax, float& ay, float& az, float& aw) {
    union { float f; __half2 h; } u0, u1;
    u0.f = raw.x; u1.f = raw.y;
    float2 f01 = __half22float2(u0.h);
    float2 f23 = __half22float2(u1.h);
    ax += f01.x; ay += f01.y; az += f23.x; aw += f23.y;
}

__global__ __launch_bounds__(256) void k_aggregate_h(const __half* __restrict__ Hs, const int* __restrict__ csr,
                                                     const int* __restrict__ rowstart, const float* __restrict__ dinv,
                                                     const float* __restrict__ bias, float* __restrict__ out, int N) {
    int node = blockIdx.x * 8 + (threadIdx.x >> 5);
    int lane = threadIdx.x & 31;
    int c = lane << 2;
    if (node >= N) return;

    int s0 = rowstart[node], s1 = rowstart[node + 1];
    float ax = 0.f, ay = 0.f, az = 0.f, aw = 0.f;

    int j = s0;
    for (; j + 8 <= s1; j += 8) {
        int i0 = csr[j + 0], i1 = csr[j + 1], i2 = csr[j + 2], i3 = csr[j + 3];
        int i4 = csr[j + 4], i5 = csr[j + 5], i6 = csr[j + 6], i7 = csr[j + 7];
        float2 r0 = *(const float2*)(Hs + (size_t)i0 * 128 + c);
        float2 r1 = *(const float2*)(Hs + (size_t)i1 * 128 + c);
        float2 r2 = *(const float2*)(Hs + (size_t)i2 * 128 + c);
        float2 r3 = *(const float2*)(Hs + (size_t)i3 * 128 + c);
        float2 r4 = *(const float2*)(Hs + (size_t)i4 * 128 + c);
        float2 r5 = *(const float2*)(Hs + (size_t)i5 * 128 + c);
        float2 r6 = *(const float2*)(Hs + (size_t)i6 * 128 + c);
        float2 r7 = *(const float2*)(Hs + (size_t)i7 * 128 + c);
        acc_h4(r0, ax, ay, az, aw); acc_h4(r1, ax, ay, az, aw);
        acc_h4(r2, ax, ay, az, aw); acc_h4(r3, ax, ay, az, aw);
        acc_h4(r4, ax, ay, az, aw); acc_h4(r5, ax, ay, az, aw);
        acc_h4(r6, ax, ay, az, aw); acc_h4(r7, ax, ay, az, aw);
    }
    for (; j < s1; j++) {
        int s = csr[j];
        float2 r = *(const float2*)(Hs + (size_t)s * 128 + c);
        acc_h4(r, ax, ay, az, aw);
    }

    float2 rs = *(const float2*)(Hs + (size_t)node * 128 + c);
    acc_h4(rs, ax, ay, az, aw);

    float dn = dinv[node];
    float4 b4 = *(const float4*)(bias + c);
    float4 r;
    r.x = ax * dn + b4.x;
    r.y = ay * dn + b4.y;
    r.z = az * dn + b4.z;
    r.w = aw * dn + b4.w;
    *(float4*)(out + (size_t)node * 128 + c) = r;
}

// ---------------- aggregation, fp32 (layer 3, D=40) ----------------

template<int TPN>
__global__ __launch_bounds__(256) void k_aggregate(const float* __restrict__ Hs, const int* __restrict__ csr,
                                                   const int* __restrict__ rowstart, const float* __restrict__ dinv,
                                                   const float* __restrict__ bias, float* __restrict__ out,
                                                   int N, int D) {
    constexpr int NPB = 256 / TPN;
    int node = blockIdx.x * NPB + threadIdx.x / TPN;
    int lane = threadIdx.x % TPN;
    int c = lane << 2;
    if (node >= N) return;
    bool act = c < D;

    int s0 = rowstart[node], s1 = rowstart[node + 1];
    float ax = 0.f, ay = 0.f, az = 0.f, aw = 0.f;

    int j = s0;
    for (; j + 8 <= s1; j += 8) {
        int i0 = csr[j + 0], i1 = csr[j + 1], i2 = csr[j + 2], i3 = csr[j + 3];
        int i4 = csr[j + 4], i5 = csr[j + 5], i6 = csr[j + 6], i7 = csr[j + 7];
        if (act) {
            float4 v0 = *(const float4*)(Hs + (size_t)i0 * D + c);
            float4 v1 = *(const float4*)(Hs + (size_t)i1 * D + c);
            float4 v2 = *(const float4*)(Hs + (size_t)i2 * D + c);
            float4 v3 = *(const float4*)(Hs + (size_t)i3 * D + c);
            float4 v4 = *(const float4*)(Hs + (size_t)i4 * D + c);
            float4 v5 = *(const float4*)(Hs + (size_t)i5 * D + c);
            float4 v6 = *(const float4*)(Hs + (size_t)i6 * D + c);
            float4 v7 = *(const float4*)(Hs + (size_t)i7 * D + c);
            ax += v0.x; ay += v0.y; az += v0.z; aw += v0.w;
            ax += v1.x; ay += v1.y; az += v1.z; aw += v1.w;
            ax += v2.x; ay += v2.y; az += v2.z; aw += v2.w;
            ax += v3.x; ay += v3.y; az += v3.z; aw += v3.w;
            ax += v4.x; ay += v4.y; az += v4.z; aw += v4.w;
            ax += v5.x; ay += v5.y; az += v5.z; aw += v5.w;
            ax += v6.x; ay += v6.y; az += v6.z; aw += v6.w;
            ax += v7.x; ay += v7.y; az += v7.z; aw += v7.w;
        }
    }
    for (; j < s1; j++) {
        int s = csr[j];
        if (act) {
            float4 v = *(const float4*)(Hs + (size_t)s * D + c);
            ax += v.x; ay += v.y; az += v.z; aw += v.w;
        }
    }

    if (act) {
        float4 self = *(const float4*)(Hs + (size_t)node * D + c);
        float dn = dinv[node];
        float4 b4 = *(const float4*)(bias + c);
        float4 r;
        r.x = (ax + self.x) * dn + b4.x;
        r.y = (ay + self.y) * dn + b4.y;
        r.z = (az + self.z) * dn + b4.z;
        r.w = (aw + self.w) * dn + b4.w;
        *(float4*)(out + (size_t)node * D + c) = r;
    }
}

// ---------------- BatchNorm stats + prep ----------------

__global__ __launch_bounds__(256) void k_bn_stats(const float* __restrict__ H, float* __restrict__ sums, int N) {
    __shared__ float ls[256], ls2[256];
    int c = threadIdx.x & 127;
    int half = threadIdx.x >> 7;
    float s = 0.f, s2 = 0.f;
    for (int r = blockIdx.x * 2 + half; r < N; r += gridDim.x * 2) {
        float v = H[(size_t)r * 128 + c];
        s += v; s2 += v * v;
    }
    ls[threadIdx.x] = s; ls2[threadIdx.x] = s2;
    __syncthreads();
    if (threadIdx.x < 128) {
        atomicAdd(&sums[c], ls[threadIdx.x] + ls[threadIdx.x + 128]);
        atomicAdd(&sums[128 + c], ls2[threadIdx.x] + ls2[threadIdx.x + 128]);
    }
}

__global__ __launch_bounds__(128) void k_bn_prep(const float* __restrict__ sums, const float* __restrict__ g,
                                                 const float* __restrict__ bt, float* __restrict__ wsh, int N) {
    int c = threadIdx.x;
    float invN = 1.0f / (float)N;
    float mu = sums[c] * invN;
    float var = sums[128 + c] * invN - mu * mu;
    float w = rsqrtf(var + 1e-5f) * g[c];
    wsh[c] = w;
    wsh[128 + c] = bt[c] - mu * w;
}

// ---------------- log_softmax over rows of D (<=64) ----------------

__global__ __launch_bounds__(256) void k_logsoftmax(float* __restrict__ out, int N, int D) {
    int wid = threadIdx.x >> 6;
    int lane = threadIdx.x & 63;
    int row = blockIdx.x * 4 + wid;
    if (row >= N) return;
    float v = (lane < D) ? out[(size_t)row * D + lane] : -1e30f;
    float m = v;
#pragma unroll
    for (int off = 32; off; off >>= 1) m = fmaxf(m, __shfl_xor(m, off, 64));
    float e = (lane < D) ? expf(v - m) : 0.f;
    float s = e;
#pragma unroll
    for (int off = 32; off; off >>= 1) s += __shfl_xor(s, off, 64);
    if (lane < D) out[(size_t)row * D + lane] = (v - m) - logf(s);
}

// ---------------- launch ----------------

extern "C" void kernel_launch(void* const* d_in, const int* in_sizes, int n_in,
                              void* d_out, int out_size, void* d_ws, size_t ws_size,
                              hipStream_t stream) {
    const float* x   = (const float*)d_in[0];
    const int*   ei  = (const int*)d_in[1];
    const float* W0  = (const float*)d_in[2];
    const float* b0  = (const float*)d_in[3];
    const float* W1  = (const float*)d_in[4];
    const float* b1  = (const float*)d_in[5];
    const float* W2  = (const float*)d_in[6];
    const float* b2  = (const float*)d_in[7];
    const float* g0  = (const float*)d_in[8];
    const float* bt0 = (const float*)d_in[9];
    const float* g1  = (const float*)d_in[10];
    const float* bt1 = (const float*)d_in[11];
    float* out = (float*)d_out;

    int N    = in_sizes[0] / 128;
    int E    = in_sizes[1] / 2;
    int DOUT = in_sizes[7];

    const int* srcp = ei;
    const int* dstp = ei + E;

    size_t off = 0;
    auto carve = [&](size_t bytes) { size_t o = off; off += (bytes + 255) & ~(size_t)255; return (char*)d_ws + o; };
    int*   cnt      = (int*)carve((size_t)N * 4);
    int*   rowstart = (int*)carve((size_t)(N + 1) * 4);
    int*   cursor   = (int*)carve((size_t)N * 4);
    int*   csr      = (int*)carve((size_t)E * 4);
    float* dinv     = (float*)carve((size_t)N * 4);
    float* stats    = (float*)carve(256 * 4);
    float* wsh0     = (float*)carve(256 * 4);
    float* wsh1     = (float*)carve(256 * 4);
    int*   bsum     = (int*)carve(64 * 4);
    int*   boff     = (int*)carve(64 * 4);
    float* Hg       = (float*)carve((size_t)N * 128 * 4);   // fp32 view (layer 3)
    float* Ha       = (float*)carve((size_t)N * 128 * 4);
    __half* HgH     = (__half*)Hg;                           // fp16 view (layers 1-2)

    hipMemsetAsync(cnt, 0, (size_t)N * 4, stream);
    hipMemsetAsync(cursor, 0, (size_t)N * 4, stream);

    int SB = (N + 4095) / 4096;

    k_count<<<(E + 255) / 256, 256, 0, stream>>>(dstp, cnt, E);
    k_dinv<<<(N + 255) / 256, 256, 0, stream>>>(cnt, dinv, N);
    k_scan_sum<<<SB, 256, 0, stream>>>(cnt, bsum, N);
    k_scan_top<<<1, 64, 0, stream>>>(bsum, boff, rowstart + N, SB);
    k_scan_apply<<<SB, 256, 0, stream>>>(cnt, boff, rowstart, N);
    k_scatter<<<(E + 255) / 256, 256, 0, stream>>>(srcp, dstp, rowstart, cursor, csr, E);

    int gemm_blocks = (N + 63) / 64;
    int aggH_blocks = (N + 7) / 8;     // fp16, 8 nodes/block
    int aggO_blocks = (N + 15) / 16;   // fp32, TPN=16

    // layer 1 (BN+ReLU applied inside next GEMM's A-load)
    k_gemm2<__half><<<gemm_blocks, 256, 0, stream>>>(x, W0, nullptr, dinv, HgH, N, 128);
    k_aggregate_h<<<aggH_blocks, 256, 0, stream>>>(HgH, csr, rowstart, dinv, b0, Ha, N);
    hipMemsetAsync(stats, 0, 256 * 4, stream);
    k_bn_stats<<<512, 256, 0, stream>>>(Ha, stats, N);
    k_bn_prep<<<1, 128, 0, stream>>>(stats, g0, bt0, wsh0, N);

    // layer 2
    k_gemm2<__half><<<gemm_blocks, 256, 0, stream>>>(Ha, W1, wsh0, dinv, HgH, N, 128);
    k_aggregate_h<<<aggH_blocks, 256, 0, stream>>>(HgH, csr, rowstart, dinv, b1, Ha, N);
    hipMemsetAsync(stats, 0, 256 * 4, stream);
    k_bn_stats<<<512, 256, 0, stream>>>(Ha, stats, N);
    k_bn_prep<<<1, 128, 0, stream>>>(stats, g1, bt1, wsh1, N);

    // layer 3 (fp32 path)
    k_gemm2<float><<<gemm_blocks, 256, 0, stream>>>(Ha, W2, wsh1, dinv, Hg, N, DOUT);
    k_aggregate<16><<<aggO_blocks, 256, 0, stream>>>(Hg, csr, rowstart, dinv, b2, out, N, DOUT);
    k_logsoftmax<<<(N + 3) / 4, 256, 0, stream>>>(out, N, DOUT);
}

// Round 6
// 335.559 us; speedup vs baseline: 2.5704x; 1.0426x over previous
//
#include <hip/hip_runtime.h>
#include <hip/hip_fp16.h>
#include <cstdint>

typedef _Float16 f16x8 __attribute__((ext_vector_type(8)));
typedef float f32x4 __attribute__((ext_vector_type(4)));

// ---------------- graph preprocessing ----------------

__global__ __launch_bounds__(256) void k_count(const int* __restrict__ dst, int* __restrict__ cnt, int E) {
    int e = blockIdx.x * 256 + threadIdx.x;
    if (e < E) atomicAdd(&cnt[dst[e]], 1);
}

__global__ __launch_bounds__(256) void k_dinv(const int* __restrict__ cnt, float* __restrict__ dinv, int N) {
    int i = blockIdx.x * 256 + threadIdx.x;
    if (i < N) dinv[i] = rsqrtf((float)(cnt[i] + 1));   // +1 self-loop
}

// ---- hierarchical exclusive scan: cnt[N] -> rowstart[N+1], 4096 elems/block ----

__global__ __launch_bounds__(256) void k_scan_sum(const int* __restrict__ cnt, int* __restrict__ bsum, int N) {
    int base = blockIdx.x * 4096 + threadIdx.x * 16;
    int s = 0;
    if (base + 16 <= N) {
        const int4* p = (const int4*)(cnt + base);
        int4 a = p[0], b = p[1], c = p[2], d = p[3];
        s = a.x + a.y + a.z + a.w + b.x + b.y + b.z + b.w
          + c.x + c.y + c.z + c.w + d.x + d.y + d.z + d.w;
    } else {
        for (int i = base; i < N; i++) s += cnt[i];
    }
    __shared__ int ws[4];
#pragma unroll
    for (int off = 32; off; off >>= 1) s += __shfl_down(s, off, 64);
    if ((threadIdx.x & 63) == 0) ws[threadIdx.x >> 6] = s;
    __syncthreads();
    if (threadIdx.x == 0) bsum[blockIdx.x] = ws[0] + ws[1] + ws[2] + ws[3];
}

__global__ void k_scan_top(const int* __restrict__ bsum, int* __restrict__ boff,
                           int* __restrict__ rowstartN, int B) {
    if (threadIdx.x == 0) {
        int run = 0;
        for (int b = 0; b < B; b++) { boff[b] = run; run += bsum[b]; }
        *rowstartN = run;
    }
}

__global__ __launch_bounds__(256) void k_scan_apply(const int* __restrict__ cnt, const int* __restrict__ boff,
                                                    int* __restrict__ rowstart, int N) {
    int t = threadIdx.x;
    int base = blockIdx.x * 4096 + t * 16;
    int v[16];
    int s = 0;
    if (base + 16 <= N) {
        const int4* p = (const int4*)(cnt + base);
        int4 q0 = p[0], q1 = p[1], q2 = p[2], q3 = p[3];
        int e[16] = {q0.x, q0.y, q0.z, q0.w, q1.x, q1.y, q1.z, q1.w,
                     q2.x, q2.y, q2.z, q2.w, q3.x, q3.y, q3.z, q3.w};
#pragma unroll
        for (int j = 0; j < 16; j++) { v[j] = s; s += e[j]; }
    } else {
#pragma unroll
        for (int j = 0; j < 16; j++) { int i = base + j; int x = (i < N) ? cnt[i] : 0; v[j] = s; s += x; }
    }
    __shared__ int ls[256];
    ls[t] = s;
    __syncthreads();
    for (int off = 1; off < 256; off <<= 1) {
        int o = (t >= off) ? ls[t - off] : 0;
        __syncthreads();
        ls[t] += o;
        __syncthreads();
    }
    int excl = ls[t] - s + boff[blockIdx.x];
    if (base + 16 <= N) {
        int w[16];
#pragma unroll
        for (int j = 0; j < 16; j++) w[j] = v[j] + excl;
        int4* p = (int4*)(rowstart + base);
        p[0] = make_int4(w[0], w[1], w[2], w[3]);
        p[1] = make_int4(w[4], w[5], w[6], w[7]);
        p[2] = make_int4(w[8], w[9], w[10], w[11]);
        p[3] = make_int4(w[12], w[13], w[14], w[15]);
    } else {
        for (int j = 0; j < 16; j++) { int i = base + j; if (i < N) rowstart[i] = v[j] + excl; }
    }
}

__global__ __launch_bounds__(256) void k_scatter(const int* __restrict__ src, const int* __restrict__ dst,
                                                 const int* __restrict__ rowstart, int* __restrict__ cursor,
                                                 int* __restrict__ csr, int E) {
    int e = blockIdx.x * 256 + threadIdx.x;
    if (e >= E) return;
    int d = dst[e];
    int pos = rowstart[d] + atomicAdd(&cursor[d], 1);
    csr[pos] = src[e];
}

// ---------------- dtype helpers ----------------

__device__ inline void store1f(float* p, float v) { *p = v; }
__device__ inline void store1f(__half* p, float v) { *p = __float2half(v); }

// fp32 -> fp16, 8 elems/thread
__global__ __launch_bounds__(256) void k_f2h(const float* __restrict__ in, __half* __restrict__ out, size_t n8) {
    size_t i = (size_t)blockIdx.x * 256 + threadIdx.x;
    if (i >= n8) return;
    const float4* p = (const float4*)(in + i * 8);
    float4 a = p[0], b = p[1];
    union { __half2 h[4]; float4 f; } u;
    u.h[0] = __floats2half2_rn(a.x, a.y);
    u.h[1] = __floats2half2_rn(a.z, a.w);
    u.h[2] = __floats2half2_rn(b.x, b.y);
    u.h[3] = __floats2half2_rn(b.z, b.w);
    *(float4*)(out + i * 8) = u.f;
}

// W[k][c] fp32 -> Wt[c][k] fp16, zero-padded to NCpad cols
__global__ __launch_bounds__(256) void k_wt(const float* __restrict__ W, __half* __restrict__ Wt, int NC, int NCpad) {
    int idx = blockIdx.x * 256 + threadIdx.x;   // over NCpad*128
    if (idx >= NCpad * 128) return;
    int c = idx >> 7, k = idx & 127;
    Wt[idx] = (c < NC) ? __float2half(W[k * NC + c]) : __float2half(0.f);
}

// ---------------- MFMA GEMM ----------------
// C[M x NC] = (act(A) @ W) * dscale[row]; A fp16 [M][128]; Wt fp16 [CT*16][128] (col-major W).
// act = BN-affine+ReLU (fp32) if wsh != null. One 16-row tile per wave, 4 waves/block.
// All of Wt hoisted into registers (CT*4 frags); A frags read directly from global
// (each a-load: 16 rows x 64B contiguous = fully-utilized lines).

template<int CT, typename OutT>
__global__ __launch_bounds__(256) void k_gemm_mfma(const __half* __restrict__ A,
                                                   const __half* __restrict__ Wt,
                                                   const float* __restrict__ wsh,
                                                   const float* __restrict__ dscale,
                                                   OutT* __restrict__ C, int M, int NC) {
    int lane = threadIdx.x & 63;
    int r0 = blockIdx.x * 64 + (threadIdx.x >> 6) * 16;
    if (r0 >= M) return;
    int lrow = lane & 15;            // A-row / B-col within tile
    int lk = (lane >> 4) << 3;       // k sub-offset 0,8,16,24

    f16x8 b[CT][4];
#pragma unroll
    for (int c = 0; c < CT; c++)
#pragma unroll
        for (int kt = 0; kt < 4; kt++)
            b[c][kt] = *(const f16x8*)(Wt + (size_t)(c * 16 + lrow) * 128 + kt * 32 + lk);

    f32x4 acc[CT];
#pragma unroll
    for (int c = 0; c < CT; c++) acc[c] = f32x4{0.f, 0.f, 0.f, 0.f};

    int row = r0 + lrow;
    bool rv = (row < M);
    const __half* Arow = A + (size_t)(rv ? row : 0) * 128 + lk;

#pragma unroll
    for (int kt = 0; kt < 4; kt++) {
        f16x8 a = *(const f16x8*)(Arow + kt * 32);
        if (!rv) a = f16x8{};
        if (wsh) {
            float4 w0 = *(const float4*)(wsh + kt * 32 + lk);
            float4 w1 = *(const float4*)(wsh + kt * 32 + lk + 4);
            float4 s0 = *(const float4*)(wsh + 128 + kt * 32 + lk);
            float4 s1 = *(const float4*)(wsh + 128 + kt * 32 + lk + 4);
            float wv[8] = {w0.x, w0.y, w0.z, w0.w, w1.x, w1.y, w1.z, w1.w};
            float sv[8] = {s0.x, s0.y, s0.z, s0.w, s1.x, s1.y, s1.z, s1.w};
#pragma unroll
            for (int j = 0; j < 8; j++)
                a[j] = (_Float16)fmaxf(fmaf((float)a[j], wv[j], sv[j]), 0.f);
        }
#pragma unroll
        for (int c = 0; c < CT; c++)
            acc[c] = __builtin_amdgcn_mfma_f32_16x16x32_f16(a, b[c][kt], acc[c], 0, 0, 0);
    }

    // C/D layout: col = lane&15 (within tile), row = (lane>>4)*4 + reg
    int rbase = r0 + ((lane >> 4) << 2);
    float4 ds4 = *(const float4*)(dscale + rbase);   // workspace padded; OOB lanes guarded below
    float dsv[4] = {ds4.x, ds4.y, ds4.z, ds4.w};
#pragma unroll
    for (int c = 0; c < CT; c++) {
        int col = c * 16 + lrow;
        if (col >= NC) continue;
#pragma unroll
        for (int reg = 0; reg < 4; reg++) {
            int r = rbase + reg;
            if (r < M) store1f(C + (size_t)r * NC + col, acc[c][reg] * dsv[reg]);
        }
    }
}

// ---------------- aggregation, fp16 gather (D=128), fp16 out ----------------

__device__ inline void acc_h4(float2 raw, float& ax, float& ay, float& az, float& aw) {
    union { float f; __half2 h; } u0, u1;
    u0.f = raw.x; u1.f = raw.y;
    float2 f01 = __half22float2(u0.h);
    float2 f23 = __half22float2(u1.h);
    ax += f01.x; ay += f01.y; az += f23.x; aw += f23.y;
}

__global__ __launch_bounds__(256) void k_aggregate_h(const __half* __restrict__ Hs, const int* __restrict__ csr,
                                                     const int* __restrict__ rowstart, const float* __restrict__ dinv,
                                                     const float* __restrict__ bias, __half* __restrict__ out, int N) {
    int node = blockIdx.x * 8 + (threadIdx.x >> 5);
    int lane = threadIdx.x & 31;
    int c = lane << 2;
    if (node >= N) return;

    int s0 = rowstart[node], s1 = rowstart[node + 1];
    float ax = 0.f, ay = 0.f, az = 0.f, aw = 0.f;

    int j = s0;
    for (; j + 8 <= s1; j += 8) {
        int i0 = csr[j + 0], i1 = csr[j + 1], i2 = csr[j + 2], i3 = csr[j + 3];
        int i4 = csr[j + 4], i5 = csr[j + 5], i6 = csr[j + 6], i7 = csr[j + 7];
        float2 r0 = *(const float2*)(Hs + (size_t)i0 * 128 + c);
        float2 r1 = *(const float2*)(Hs + (size_t)i1 * 128 + c);
        float2 r2 = *(const float2*)(Hs + (size_t)i2 * 128 + c);
        float2 r3 = *(const float2*)(Hs + (size_t)i3 * 128 + c);
        float2 r4 = *(const float2*)(Hs + (size_t)i4 * 128 + c);
        float2 r5 = *(const float2*)(Hs + (size_t)i5 * 128 + c);
        float2 r6 = *(const float2*)(Hs + (size_t)i6 * 128 + c);
        float2 r7 = *(const float2*)(Hs + (size_t)i7 * 128 + c);
        acc_h4(r0, ax, ay, az, aw); acc_h4(r1, ax, ay, az, aw);
        acc_h4(r2, ax, ay, az, aw); acc_h4(r3, ax, ay, az, aw);
        acc_h4(r4, ax, ay, az, aw); acc_h4(r5, ax, ay, az, aw);
        acc_h4(r6, ax, ay, az, aw); acc_h4(r7, ax, ay, az, aw);
    }
    for (; j < s1; j++) {
        int s = csr[j];
        float2 r = *(const float2*)(Hs + (size_t)s * 128 + c);
        acc_h4(r, ax, ay, az, aw);
    }

    float2 rs = *(const float2*)(Hs + (size_t)node * 128 + c);
    acc_h4(rs, ax, ay, az, aw);

    float dn = dinv[node];
    float4 b4 = *(const float4*)(bias + c);
    union { __half2 h[2]; float2 f; } u;
    u.h[0] = __floats2half2_rn(ax * dn + b4.x, ay * dn + b4.y);
    u.h[1] = __floats2half2_rn(az * dn + b4.z, aw * dn + b4.w);
    *(float2*)(out + (size_t)node * 128 + c) = u.f;
}

// ---------------- aggregation, fp32 (layer 3, D=40) ----------------

template<int TPN>
__global__ __launch_bounds__(256) void k_aggregate(const float* __restrict__ Hs, const int* __restrict__ csr,
                                                   const int* __restrict__ rowstart, const float* __restrict__ dinv,
                                                   const float* __restrict__ bias, float* __restrict__ out,
                                                   int N, int D) {
    constexpr int NPB = 256 / TPN;
    int node = blockIdx.x * NPB + threadIdx.x / TPN;
    int lane = threadIdx.x % TPN;
    int c = lane << 2;
    if (node >= N) return;
    bool act = c < D;

    int s0 = rowstart[node], s1 = rowstart[node + 1];
    float ax = 0.f, ay = 0.f, az = 0.f, aw = 0.f;

    int j = s0;
    for (; j + 8 <= s1; j += 8) {
        int i0 = csr[j + 0], i1 = csr[j + 1], i2 = csr[j + 2], i3 = csr[j + 3];
        int i4 = csr[j + 4], i5 = csr[j + 5], i6 = csr[j + 6], i7 = csr[j + 7];
        if (act) {
            float4 v0 = *(const float4*)(Hs + (size_t)i0 * D + c);
            float4 v1 = *(const float4*)(Hs + (size_t)i1 * D + c);
            float4 v2 = *(const float4*)(Hs + (size_t)i2 * D + c);
            float4 v3 = *(const float4*)(Hs + (size_t)i3 * D + c);
            float4 v4 = *(const float4*)(Hs + (size_t)i4 * D + c);
            float4 v5 = *(const float4*)(Hs + (size_t)i5 * D + c);
            float4 v6 = *(const float4*)(Hs + (size_t)i6 * D + c);
            float4 v7 = *(const float4*)(Hs + (size_t)i7 * D + c);
            ax += v0.x; ay += v0.y; az += v0.z; aw += v0.w;
            ax += v1.x; ay += v1.y; az += v1.z; aw += v1.w;
            ax += v2.x; ay += v2.y; az += v2.z; aw += v2.w;
            ax += v3.x; ay += v3.y; az += v3.z; aw += v3.w;
            ax += v4.x; ay += v4.y; az += v4.z; aw += v4.w;
            ax += v5.x; ay += v5.y; az += v5.z; aw += v5.w;
            ax += v6.x; ay += v6.y; az += v6.z; aw += v6.w;
            ax += v7.x; ay += v7.y; az += v7.z; aw += v7.w;
        }
    }
    for (; j < s1; j++) {
        int s = csr[j];
        if (act) {
            float4 v = *(const float4*)(Hs + (size_t)s * D + c);
            ax += v.x; ay += v.y; az += v.z; aw += v.w;
        }
    }

    if (act) {
        float4 self = *(const float4*)(Hs + (size_t)node * D + c);
        float dn = dinv[node];
        float4 b4 = *(const float4*)(bias + c);
        float4 r;
        r.x = (ax + self.x) * dn + b4.x;
        r.y = (ay + self.y) * dn + b4.y;
        r.z = (az + self.z) * dn + b4.z;
        r.w = (aw + self.w) * dn + b4.w;
        *(float4*)(out + (size_t)node * D + c) = r;
    }
}

// ---------------- BatchNorm stats (fp16 input) + prep ----------------

__global__ __launch_bounds__(256) void k_bn_stats_h(const __half* __restrict__ H, float* __restrict__ sums, int N) {
    __shared__ float ls[256], ls2[256];
    int c = threadIdx.x & 127;
    int half = threadIdx.x >> 7;
    float s = 0.f, s2 = 0.f;
    for (int r = blockIdx.x * 2 + half; r < N; r += gridDim.x * 2) {
        float v = __half2float(H[(size_t)r * 128 + c]);
        s += v; s2 += v * v;
    }
    ls[threadIdx.x] = s; ls2[threadIdx.x] = s2;
    __syncthreads();
    if (threadIdx.x < 128) {
        atomicAdd(&sums[c], ls[threadIdx.x] + ls[threadIdx.x + 128]);
        atomicAdd(&sums[128 + c], ls2[threadIdx.x] + ls2[threadIdx.x + 128]);
    }
}

__global__ __launch_bounds__(128) void k_bn_prep(const float* __restrict__ sums, const float* __restrict__ g,
                                                 const float* __restrict__ bt, float* __restrict__ wsh, int N) {
    int c = threadIdx.x;
    float invN = 1.0f / (float)N;
    float mu = sums[c] * invN;
    float var = sums[128 + c] * invN - mu * mu;
    float w = rsqrtf(var + 1e-5f) * g[c];
    wsh[c] = w;
    wsh[128 + c] = bt[c] - mu * w;
}

// ---------------- log_softmax over rows of D (<=64) ----------------

__global__ __launch_bounds__(256) void k_logsoftmax(float* __restrict__ out, int N, int D) {
    int wid = threadIdx.x >> 6;
    int lane = threadIdx.x & 63;
    int row = blockIdx.x * 4 + wid;
    if (row >= N) return;
    float v = (lane < D) ? out[(size_t)row * D + lane] : -1e30f;
    float m = v;
#pragma unroll
    for (int off = 32; off; off >>= 1) m = fmaxf(m, __shfl_xor(m, off, 64));
    float e = (lane < D) ? expf(v - m) : 0.f;
    float s = e;
#pragma unroll
    for (int off = 32; off; off >>= 1) s += __shfl_xor(s, off, 64);
    if (lane < D) out[(size_t)row * D + lane] = (v - m) - logf(s);
}

// ---------------- launch ----------------

extern "C" void kernel_launch(void* const* d_in, const int* in_sizes, int n_in,
                              void* d_out, int out_size, void* d_ws, size_t ws_size,
                              hipStream_t stream) {
    const float* x   = (const float*)d_in[0];
    const int*   ei  = (const int*)d_in[1];
    const float* W0  = (const float*)d_in[2];
    const float* b0  = (const float*)d_in[3];
    const float* W1  = (const float*)d_in[4];
    const float* b1  = (const float*)d_in[5];
    const float* W2  = (const float*)d_in[6];
    const float* b2  = (const float*)d_in[7];
    const float* g0  = (const float*)d_in[8];
    const float* bt0 = (const float*)d_in[9];
    const float* g1  = (const float*)d_in[10];
    const float* bt1 = (const float*)d_in[11];
    float* out = (float*)d_out;

    int N    = in_sizes[0] / 128;
    int E    = in_sizes[1] / 2;
    int DOUT = in_sizes[7];          // 40

    const int* srcp = ei;
    const int* dstp = ei + E;

    size_t off = 0;
    auto carve = [&](size_t bytes) { size_t o = off; off += (bytes + 255) & ~(size_t)255; return (char*)d_ws + o; };
    int*    cnt      = (int*)carve((size_t)N * 4);
    int*    rowstart = (int*)carve((size_t)(N + 1) * 4);
    int*    cursor   = (int*)carve((size_t)N * 4);
    int*    csr      = (int*)carve((size_t)E * 4);
    float*  dinv     = (float*)carve((size_t)N * 4);
    float*  stats    = (float*)carve(256 * 4);
    float*  wsh0     = (float*)carve(256 * 4);
    float*  wsh1     = (float*)carve(256 * 4);
    int*    bsum     = (int*)carve(64 * 4);
    int*    boff     = (int*)carve(64 * 4);
    __half* xh       = (__half*)carve((size_t)N * 128 * 2);
    __half* W0t      = (__half*)carve(128 * 128 * 2);
    __half* W1t      = (__half*)carve(128 * 128 * 2);
    __half* W2t      = (__half*)carve(48 * 128 * 2);
    __half* HgH      = (__half*)carve((size_t)N * 128 * 2);
    __half* HaH      = (__half*)carve((size_t)N * 128 * 2);
    float*  Hg32     = (float*)carve((size_t)N * 40 * 4);

    hipMemsetAsync(cnt, 0, (size_t)N * 4, stream);
    hipMemsetAsync(cursor, 0, (size_t)N * 4, stream);

    int SB = (N + 4095) / 4096;

    k_count<<<(E + 255) / 256, 256, 0, stream>>>(dstp, cnt, E);
    k_dinv<<<(N + 255) / 256, 256, 0, stream>>>(cnt, dinv, N);
    k_scan_sum<<<SB, 256, 0, stream>>>(cnt, bsum, N);
    k_scan_top<<<1, 64, 0, stream>>>(bsum, boff, rowstart + N, SB);
    k_scan_apply<<<SB, 256, 0, stream>>>(cnt, boff, rowstart, N);
    k_scatter<<<(E + 255) / 256, 256, 0, stream>>>(srcp, dstp, rowstart, cursor, csr, E);

    // fp16 conversions / weight transposes
    size_t n8 = (size_t)N * 16;   // N*128/8
    k_f2h<<<(int)((n8 + 255) / 256), 256, 0, stream>>>(x, xh, n8);
    k_wt<<<(128 * 128 + 255) / 256, 256, 0, stream>>>(W0, W0t, 128, 128);
    k_wt<<<(128 * 128 + 255) / 256, 256, 0, stream>>>(W1, W1t, 128, 128);
    k_wt<<<(48 * 128 + 255) / 256, 256, 0, stream>>>(W2, W2t, DOUT, 48);

    int gemm_blocks = (N + 63) / 64;
    int aggH_blocks = (N + 7) / 8;
    int aggO_blocks = (N + 15) / 16;

    // layer 1 (BN+ReLU of this layer applied inside NEXT GEMM's A-fragment)
    k_gemm_mfma<8, __half><<<gemm_blocks, 256, 0, stream>>>(xh, W0t, nullptr, dinv, HgH, N, 128);
    k_aggregate_h<<<aggH_blocks, 256, 0, stream>>>(HgH, csr, rowstart, dinv, b0, HaH, N);
    hipMemsetAsync(stats, 0, 256 * 4, stream);
    k_bn_stats_h<<<512, 256, 0, stream>>>(HaH, stats, N);
    k_bn_prep<<<1, 128, 0, stream>>>(stats, g0, bt0, wsh0, N);

    // layer 2
    k_gemm_mfma<8, __half><<<gemm_blocks, 256, 0, stream>>>(HaH, W1t, wsh0, dinv, HgH, N, 128);
    k_aggregate_h<<<aggH_blocks, 256, 0, stream>>>(HgH, csr, rowstart, dinv, b1, HaH, N);
    hipMemsetAsync(stats, 0, 256 * 4, stream);
    k_bn_stats_h<<<512, 256, 0, stream>>>(HaH, stats, N);
    k_bn_prep<<<1, 128, 0, stream>>>(stats, g1, bt1, wsh1, N);

    // layer 3 (fp32 out, D=40 padded to 48 col-tiles)
    k_gemm_mfma<3, float><<<gemm_blocks, 256, 0, stream>>>(HaH, W2t, wsh1, dinv, Hg32, N, DOUT);
    k_aggregate<16><<<aggO_blocks, 256, 0, stream>>>(Hg32, csr, rowstart, dinv, b2, out, N, DOUT);
    k_logsoftmax<<<(N + 3) / 4, 256, 0, stream>>>(out, N, DOUT);
}

// Round 7
// 317.404 us; speedup vs baseline: 2.7175x; 1.0572x over previous
//
#include <hip/hip_runtime.h>
#include <hip/hip_fp16.h>
#include <cstdint>

typedef _Float16 f16x8 __attribute__((ext_vector_type(8)));
typedef float f32x4 __attribute__((ext_vector_type(4)));

// ---------------- graph preprocessing ----------------

__global__ __launch_bounds__(256) void k_count(const int* __restrict__ dst, int* __restrict__ cnt, int E) {
    int e = blockIdx.x * 256 + threadIdx.x;
    if (e < E) atomicAdd(&cnt[dst[e]], 1);
}

// per-4096-chunk sums of cnt
__global__ __launch_bounds__(256) void k_scan_sum(const int* __restrict__ cnt, int* __restrict__ bsum, int N) {
    int base = blockIdx.x * 4096 + threadIdx.x * 16;
    int s = 0;
    if (base + 16 <= N) {
        const int4* p = (const int4*)(cnt + base);
        int4 a = p[0], b = p[1], c = p[2], d = p[3];
        s = a.x + a.y + a.z + a.w + b.x + b.y + b.z + b.w
          + c.x + c.y + c.z + c.w + d.x + d.y + d.z + d.w;
    } else {
        for (int i = base; i < N; i++) s += cnt[i];
    }
    __shared__ int ws[4];
#pragma unroll
    for (int off = 32; off; off >>= 1) s += __shfl_down(s, off, 64);
    if ((threadIdx.x & 63) == 0) ws[threadIdx.x >> 6] = s;
    __syncthreads();
    if (threadIdx.x == 0) bsum[blockIdx.x] = ws[0] + ws[1] + ws[2] + ws[3];
}

// exclusive scan apply + rowstart[N] + dinv, fused (top-level prefix of <=16 bsums per block)
__global__ __launch_bounds__(256) void k_scan_apply(const int* __restrict__ cnt, const int* __restrict__ bsum,
                                                    int* __restrict__ rowstart, float* __restrict__ dinv,
                                                    int N, int SB) {
    __shared__ int boff_s;
    __shared__ int ls[256];
    int t = threadIdx.x;
    if (t == 0) {
        int run = 0;
        for (int i = 0; i < (int)blockIdx.x; i++) run += bsum[i];
        boff_s = run;
        if ((int)blockIdx.x == SB - 1) {
            int tot = run;
            for (int i = blockIdx.x; i < SB; i++) tot += bsum[i];
            rowstart[N] = tot;
        }
    }
    int base = blockIdx.x * 4096 + t * 16;
    int v[16], e[16];
    int s = 0;
    bool full = (base + 16 <= N);
    if (full) {
        const int4* p = (const int4*)(cnt + base);
        int4 q0 = p[0], q1 = p[1], q2 = p[2], q3 = p[3];
        int tmp[16] = {q0.x, q0.y, q0.z, q0.w, q1.x, q1.y, q1.z, q1.w,
                       q2.x, q2.y, q2.z, q2.w, q3.x, q3.y, q3.z, q3.w};
#pragma unroll
        for (int j = 0; j < 16; j++) { e[j] = tmp[j]; v[j] = s; s += e[j]; }
    } else {
#pragma unroll
        for (int j = 0; j < 16; j++) { int i = base + j; e[j] = (i < N) ? cnt[i] : 0; v[j] = s; s += e[j]; }
    }
    ls[t] = s;
    __syncthreads();
    for (int off = 1; off < 256; off <<= 1) {
        int o = (t >= off) ? ls[t - off] : 0;
        __syncthreads();
        ls[t] += o;
        __syncthreads();
    }
    int excl = ls[t] - s + boff_s;
    if (full) {
        int w[16];
        float dv[16];
#pragma unroll
        for (int j = 0; j < 16; j++) { w[j] = v[j] + excl; dv[j] = rsqrtf((float)(e[j] + 1)); }
        int4* p = (int4*)(rowstart + base);
        p[0] = make_int4(w[0], w[1], w[2], w[3]);
        p[1] = make_int4(w[4], w[5], w[6], w[7]);
        p[2] = make_int4(w[8], w[9], w[10], w[11]);
        p[3] = make_int4(w[12], w[13], w[14], w[15]);
        float4* q = (float4*)(dinv + base);
        q[0] = make_float4(dv[0], dv[1], dv[2], dv[3]);
        q[1] = make_float4(dv[4], dv[5], dv[6], dv[7]);
        q[2] = make_float4(dv[8], dv[9], dv[10], dv[11]);
        q[3] = make_float4(dv[12], dv[13], dv[14], dv[15]);
    } else {
        for (int j = 0; j < 16; j++) {
            int i = base + j;
            if (i < N) { rowstart[i] = v[j] + excl; dinv[i] = rsqrtf((float)(e[j] + 1)); }
        }
    }
}

__global__ __launch_bounds__(256) void k_scatter(const int* __restrict__ src, const int* __restrict__ dst,
                                                 const int* __restrict__ rowstart, int* __restrict__ cursor,
                                                 int* __restrict__ csr, int E) {
    int e = blockIdx.x * 256 + threadIdx.x;
    if (e >= E) return;
    int d = dst[e];
    int pos = rowstart[d] + atomicAdd(&cursor[d], 1);
    csr[pos] = src[e];
}

// ---------------- weight transposes (all 3 in one launch) ----------------
// W[k][c] fp32 -> Wt[c][k] fp16, W2 zero-padded to 48 cols.

__global__ __launch_bounds__(256) void k_wt_all(const float* __restrict__ W0, const float* __restrict__ W1,
                                                const float* __restrict__ W2,
                                                __half* __restrict__ W0t, __half* __restrict__ W1t,
                                                __half* __restrict__ W2t, int DOUT) {
    int idx = blockIdx.x * 256 + threadIdx.x;
    if (idx < 16384) {
        int c = idx >> 7, k = idx & 127;
        W0t[idx] = __float2half(W0[k * 128 + c]);
    } else if (idx < 32768) {
        int i = idx - 16384;
        int c = i >> 7, k = i & 127;
        W1t[i] = __float2half(W1[k * 128 + c]);
    } else if (idx < 32768 + 48 * 128) {
        int i = idx - 32768;
        int c = i >> 7, k = i & 127;
        W2t[i] = (c < DOUT) ? __float2half(W2[k * DOUT + c]) : __half(0);
    }
}

// ---------------- dtype helpers ----------------

__device__ inline void store1f(float* p, float v) { *p = v; }
__device__ inline void store1f(__half* p, float v) { *p = __float2half(v); }

__device__ inline f16x8 load_a8(const __half* p) { return *(const f16x8*)p; }
__device__ inline f16x8 load_a8(const float* p) {
    float4 a = *(const float4*)p;
    float4 b = *(const float4*)(p + 4);
    f16x8 r;
    r[0] = (_Float16)a.x; r[1] = (_Float16)a.y; r[2] = (_Float16)a.z; r[3] = (_Float16)a.w;
    r[4] = (_Float16)b.x; r[5] = (_Float16)b.y; r[6] = (_Float16)b.z; r[7] = (_Float16)b.w;
    return r;
}

// ---------------- MFMA GEMM ----------------
// C[M x NC] = (act(A) @ W) * dscale[row]; act = BN(from raw sums)+ReLU if sums != null.
// A: [M][128] fp16 or fp32. Wt: [CT*16][128] fp16 (col-major W, padded).
// One 16-row tile per wave, 4 waves/block. Wt hoisted to registers.

template<int CT, typename InT, typename OutT>
__global__ __launch_bounds__(256) void k_gemm_mfma(const InT* __restrict__ A,
                                                   const __half* __restrict__ Wt,
                                                   const float* __restrict__ sums,   // [c], [128+c]=sumsq; null = no BN
                                                   const float* __restrict__ g,
                                                   const float* __restrict__ bt,
                                                   float invN,
                                                   const float* __restrict__ dscale,
                                                   OutT* __restrict__ C, int M, int NC) {
    int lane = threadIdx.x & 63;
    int r0 = blockIdx.x * 64 + (threadIdx.x >> 6) * 16;
    if (r0 >= M) return;
    int lrow = lane & 15;            // A-row / B-col within tile
    int lk = (lane >> 4) << 3;       // k sub-offset 0,8,16,24

    f16x8 b[CT][4];
#pragma unroll
    for (int c = 0; c < CT; c++)
#pragma unroll
        for (int kt = 0; kt < 4; kt++)
            b[c][kt] = *(const f16x8*)(Wt + (size_t)(c * 16 + lrow) * 128 + kt * 32 + lk);

    f32x4 acc[CT];
#pragma unroll
    for (int c = 0; c < CT; c++) acc[c] = f32x4{0.f, 0.f, 0.f, 0.f};

    int row = r0 + lrow;
    bool rv = (row < M);
    const InT* Arow = A + (size_t)(rv ? row : 0) * 128 + lk;

#pragma unroll
    for (int kt = 0; kt < 4; kt++) {
        f16x8 a = load_a8(Arow + kt * 32);
        if (!rv) a = f16x8{};
        if (sums) {
            int ch = kt * 32 + lk;
            float4 s1a = *(const float4*)(sums + ch);
            float4 s1b = *(const float4*)(sums + ch + 4);
            float4 s2a = *(const float4*)(sums + 128 + ch);
            float4 s2b = *(const float4*)(sums + 128 + ch + 4);
            float4 ga  = *(const float4*)(g + ch);
            float4 gb  = *(const float4*)(g + ch + 4);
            float4 ba  = *(const float4*)(bt + ch);
            float4 bb  = *(const float4*)(bt + ch + 4);
            float s1v[8] = {s1a.x, s1a.y, s1a.z, s1a.w, s1b.x, s1b.y, s1b.z, s1b.w};
            float s2v[8] = {s2a.x, s2a.y, s2a.z, s2a.w, s2b.x, s2b.y, s2b.z, s2b.w};
            float gv[8]  = {ga.x, ga.y, ga.z, ga.w, gb.x, gb.y, gb.z, gb.w};
            float btv[8] = {ba.x, ba.y, ba.z, ba.w, bb.x, bb.y, bb.z, bb.w};
#pragma unroll
            for (int j = 0; j < 8; j++) {
                float mu  = s1v[j] * invN;
                float var = s2v[j] * invN - mu * mu;
                float w   = rsqrtf(var + 1e-5f) * gv[j];
                float sh  = btv[j] - mu * w;
                a[j] = (_Float16)fmaxf(fmaf((float)a[j], w, sh), 0.f);
            }
        }
#pragma unroll
        for (int c = 0; c < CT; c++)
            acc[c] = __builtin_amdgcn_mfma_f32_16x16x32_f16(a, b[c][kt], acc[c], 0, 0, 0);
    }

    // C/D layout: col = lane&15 (within tile), row = (lane>>4)*4 + reg
    int rbase = r0 + ((lane >> 4) << 2);
    float4 ds4 = *(const float4*)(dscale + rbase);
    float dsv[4] = {ds4.x, ds4.y, ds4.z, ds4.w};
#pragma unroll
    for (int c = 0; c < CT; c++) {
        int col = c * 16 + lrow;
        if (col >= NC) continue;
#pragma unroll
        for (int reg = 0; reg < 4; reg++) {
            int r = rbase + reg;
            if (r < M) store1f(C + (size_t)r * NC + col, acc[c][reg] * dsv[reg]);
        }
    }
}

// ---------------- aggregation, fp16 gather (D=128), fp16 out ----------------

__device__ inline void acc_h4(float2 raw, float& ax, float& ay, float& az, float& aw) {
    union { float f; __half2 h; } u0, u1;
    u0.f = raw.x; u1.f = raw.y;
    float2 f01 = __half22float2(u0.h);
    float2 f23 = __half22float2(u1.h);
    ax += f01.x; ay += f01.y; az += f23.x; aw += f23.y;
}

__global__ __launch_bounds__(256) void k_aggregate_h(const __half* __restrict__ Hs, const int* __restrict__ csr,
                                                     const int* __restrict__ rowstart, const float* __restrict__ dinv,
                                                     const float* __restrict__ bias, __half* __restrict__ out, int N) {
    int node = blockIdx.x * 8 + (threadIdx.x >> 5);
    int lane = threadIdx.x & 31;
    int c = lane << 2;
    if (node >= N) return;

    int s0 = rowstart[node], s1 = rowstart[node + 1];
    float ax = 0.f, ay = 0.f, az = 0.f, aw = 0.f;

    int j = s0;
    for (; j + 8 <= s1; j += 8) {
        int i0 = csr[j + 0], i1 = csr[j + 1], i2 = csr[j + 2], i3 = csr[j + 3];
        int i4 = csr[j + 4], i5 = csr[j + 5], i6 = csr[j + 6], i7 = csr[j + 7];
        float2 r0 = *(const float2*)(Hs + (size_t)i0 * 128 + c);
        float2 r1 = *(const float2*)(Hs + (size_t)i1 * 128 + c);
        float2 r2 = *(const float2*)(Hs + (size_t)i2 * 128 + c);
        float2 r3 = *(const float2*)(Hs + (size_t)i3 * 128 + c);
        float2 r4 = *(const float2*)(Hs + (size_t)i4 * 128 + c);
        float2 r5 = *(const float2*)(Hs + (size_t)i5 * 128 + c);
        float2 r6 = *(const float2*)(Hs + (size_t)i6 * 128 + c);
        float2 r7 = *(const float2*)(Hs + (size_t)i7 * 128 + c);
        acc_h4(r0, ax, ay, az, aw); acc_h4(r1, ax, ay, az, aw);
        acc_h4(r2, ax, ay, az, aw); acc_h4(r3, ax, ay, az, aw);
        acc_h4(r4, ax, ay, az, aw); acc_h4(r5, ax, ay, az, aw);
        acc_h4(r6, ax, ay, az, aw); acc_h4(r7, ax, ay, az, aw);
    }
    for (; j < s1; j++) {
        int s = csr[j];
        float2 r = *(const float2*)(Hs + (size_t)s * 128 + c);
        acc_h4(r, ax, ay, az, aw);
    }

    float2 rs = *(const float2*)(Hs + (size_t)node * 128 + c);
    acc_h4(rs, ax, ay, az, aw);

    float dn = dinv[node];
    float4 b4 = *(const float4*)(bias + c);
    union { __half2 h[2]; float2 f; } u;
    u.h[0] = __floats2half2_rn(ax * dn + b4.x, ay * dn + b4.y);
    u.h[1] = __floats2half2_rn(az * dn + b4.z, aw * dn + b4.w);
    *(float2*)(out + (size_t)node * 128 + c) = u.f;
}

// ---------------- aggregation + log_softmax, fp32 (layer 3, D<=64) ----------------
// TPN=16 lanes per node; after bias, subgroup shuffle reductions give row max/sum.

__global__ __launch_bounds__(256) void k_aggregate_lsm(const float* __restrict__ Hs, const int* __restrict__ csr,
                                                       const int* __restrict__ rowstart, const float* __restrict__ dinv,
                                                       const float* __restrict__ bias, float* __restrict__ out,
                                                       int N, int D) {
    int node = blockIdx.x * 16 + (threadIdx.x >> 4);
    int lane = threadIdx.x & 15;
    int c = lane << 2;
    if (node >= N) return;
    bool act = c < D;

    int s0 = rowstart[node], s1 = rowstart[node + 1];
    float ax = 0.f, ay = 0.f, az = 0.f, aw = 0.f;

    int j = s0;
    for (; j + 8 <= s1; j += 8) {
        int i0 = csr[j + 0], i1 = csr[j + 1], i2 = csr[j + 2], i3 = csr[j + 3];
        int i4 = csr[j + 4], i5 = csr[j + 5], i6 = csr[j + 6], i7 = csr[j + 7];
        if (act) {
            float4 v0 = *(const float4*)(Hs + (size_t)i0 * D + c);
            float4 v1 = *(const float4*)(Hs + (size_t)i1 * D + c);
            float4 v2 = *(const float4*)(Hs + (size_t)i2 * D + c);
            float4 v3 = *(const float4*)(Hs + (size_t)i3 * D + c);
            float4 v4 = *(const float4*)(Hs + (size_t)i4 * D + c);
            float4 v5 = *(const float4*)(Hs + (size_t)i5 * D + c);
            float4 v6 = *(const float4*)(Hs + (size_t)i6 * D + c);
            float4 v7 = *(const float4*)(Hs + (size_t)i7 * D + c);
            ax += v0.x; ay += v0.y; az += v0.z; aw += v0.w;
            ax += v1.x; ay += v1.y; az += v1.z; aw += v1.w;
            ax += v2.x; ay += v2.y; az += v2.z; aw += v2.w;
            ax += v3.x; ay += v3.y; az += v3.z; aw += v3.w;
            ax += v4.x; ay += v4.y; az += v4.z; aw += v4.w;
            ax += v5.x; ay += v5.y; az += v5.z; aw += v5.w;
            ax += v6.x; ay += v6.y; az += v6.z; aw += v6.w;
            ax += v7.x; ay += v7.y; az += v7.z; aw += v7.w;
        }
    }
    for (; j < s1; j++) {
        int s = csr[j];
        if (act) {
            float4 v = *(const float4*)(Hs + (size_t)s * D + c);
            ax += v.x; ay += v.y; az += v.z; aw += v.w;
        }
    }

    float4 r = make_float4(0.f, 0.f, 0.f, 0.f);
    if (act) {
        float4 self = *(const float4*)(Hs + (size_t)node * D + c);
        float dn = dinv[node];
        float4 b4 = *(const float4*)(bias + c);
        r.x = (ax + self.x) * dn + b4.x;
        r.y = (ay + self.y) * dn + b4.y;
        r.z = (az + self.z) * dn + b4.z;
        r.w = (aw + self.w) * dn + b4.w;
    }

    // subgroup (16-lane) log-softmax
    float m = act ? fmaxf(fmaxf(r.x, r.y), fmaxf(r.z, r.w)) : -1e30f;
#pragma unroll
    for (int off = 8; off; off >>= 1) m = fmaxf(m, __shfl_xor(m, off, 16));
    float es = act ? (expf(r.x - m) + expf(r.y - m) + expf(r.z - m) + expf(r.w - m)) : 0.f;
#pragma unroll
    for (int off = 8; off; off >>= 1) es += __shfl_xor(es, off, 16);
    float ls = logf(es);
    if (act) {
        float4 o = make_float4(r.x - m - ls, r.y - m - ls, r.z - m - ls, r.w - m - ls);
        *(float4*)(out + (size_t)node * D + c) = o;
    }
}

// ---------------- BatchNorm stats (fp16 input) ----------------

__global__ __launch_bounds__(256) void k_bn_stats_h(const __half* __restrict__ H, float* __restrict__ sums, int N) {
    __shared__ float ls[256], ls2[256];
    int c = threadIdx.x & 127;
    int half = threadIdx.x >> 7;
    float s = 0.f, s2 = 0.f;
    for (int r = blockIdx.x * 2 + half; r < N; r += gridDim.x * 2) {
        float v = __half2float(H[(size_t)r * 128 + c]);
        s += v; s2 += v * v;
    }
    ls[threadIdx.x] = s; ls2[threadIdx.x] = s2;
    __syncthreads();
    if (threadIdx.x < 128) {
        atomicAdd(&sums[c], ls[threadIdx.x] + ls[threadIdx.x + 128]);
        atomicAdd(&sums[128 + c], ls2[threadIdx.x] + ls2[threadIdx.x + 128]);
    }
}

// ---------------- launch ----------------

extern "C" void kernel_launch(void* const* d_in, const int* in_sizes, int n_in,
                              void* d_out, int out_size, void* d_ws, size_t ws_size,
                              hipStream_t stream) {
    const float* x   = (const float*)d_in[0];
    const int*   ei  = (const int*)d_in[1];
    const float* W0  = (const float*)d_in[2];
    const float* b0  = (const float*)d_in[3];
    const float* W1  = (const float*)d_in[4];
    const float* b1  = (const float*)d_in[5];
    const float* W2  = (const float*)d_in[6];
    const float* b2  = (const float*)d_in[7];
    const float* g0  = (const float*)d_in[8];
    const float* bt0 = (const float*)d_in[9];
    const float* g1  = (const float*)d_in[10];
    const float* bt1 = (const float*)d_in[11];
    float* out = (float*)d_out;

    int N    = in_sizes[0] / 128;
    int E    = in_sizes[1] / 2;
    int DOUT = in_sizes[7];          // 40
    float invN = 1.0f / (float)N;

    const int* srcp = ei;
    const int* dstp = ei + E;

    size_t off = 0;
    auto carve = [&](size_t bytes) { size_t o = off; off += (bytes + 255) & ~(size_t)255; return (char*)d_ws + o; };
    // zero-group (one memset): cnt, cursor, stats0, stats1
    int*    cnt      = (int*)carve((size_t)N * 4);
    int*    cursor   = (int*)carve((size_t)N * 4);
    float*  stats0   = (float*)carve(256 * 4);
    float*  stats1   = (float*)carve(256 * 4);
    size_t zero_span = (size_t)((char*)stats1 + 256 * 4 - (char*)cnt);
    int*    rowstart = (int*)carve((size_t)(N + 1) * 4);
    int*    csr      = (int*)carve((size_t)E * 4);
    float*  dinv     = (float*)carve((size_t)N * 4);
    int*    bsum     = (int*)carve(64 * 4);
    __half* W0t      = (__half*)carve(128 * 128 * 2);
    __half* W1t      = (__half*)carve(128 * 128 * 2);
    __half* W2t      = (__half*)carve(48 * 128 * 2);
    __half* HgH      = (__half*)carve((size_t)N * 128 * 2);
    __half* HaH      = (__half*)carve((size_t)N * 128 * 2);
    float*  Hg32     = (float*)carve((size_t)N * 40 * 4);

    hipMemsetAsync(cnt, 0, zero_span, stream);

    int SB = (N + 4095) / 4096;

    k_wt_all<<<(32768 + 48 * 128 + 255) / 256, 256, 0, stream>>>(W0, W1, W2, W0t, W1t, W2t, DOUT);
    k_count<<<(E + 255) / 256, 256, 0, stream>>>(dstp, cnt, E);
    k_scan_sum<<<SB, 256, 0, stream>>>(cnt, bsum, N);
    k_scan_apply<<<SB, 256, 0, stream>>>(cnt, bsum, rowstart, dinv, N, SB);
    k_scatter<<<(E + 255) / 256, 256, 0, stream>>>(srcp, dstp, rowstart, cursor, csr, E);

    int gemm_blocks = (N + 63) / 64;
    int aggH_blocks = (N + 7) / 8;
    int aggO_blocks = (N + 15) / 16;

    // layer 1 (fp32 input, no BN)
    k_gemm_mfma<8, float, __half><<<gemm_blocks, 256, 0, stream>>>(x, W0t, nullptr, nullptr, nullptr, invN, dinv, HgH, N, 128);
    k_aggregate_h<<<aggH_blocks, 256, 0, stream>>>(HgH, csr, rowstart, dinv, b0, HaH, N);
    k_bn_stats_h<<<512, 256, 0, stream>>>(HaH, stats0, N);

    // layer 2 (BN0+ReLU fused into A-fragment, from raw sums)
    k_gemm_mfma<8, __half, __half><<<gemm_blocks, 256, 0, stream>>>(HaH, W1t, stats0, g0, bt0, invN, dinv, HgH, N, 128);
    k_aggregate_h<<<aggH_blocks, 256, 0, stream>>>(HgH, csr, rowstart, dinv, b1, HaH, N);
    k_bn_stats_h<<<512, 256, 0, stream>>>(HaH, stats1, N);

    // layer 3 (BN1+ReLU fused; fp32 out; aggregate fused with log_softmax)
    k_gemm_mfma<3, __half, float><<<gemm_blocks, 256, 0, stream>>>(HaH, W2t, stats1, g1, bt1, invN, dinv, Hg32, N, DOUT);
    k_aggregate_lsm<<<aggO_blocks, 256, 0, stream>>>(Hg32, csr, rowstart, dinv, b2, out, N, DOUT);
}